// Round 17
// baseline (198.984 us; speedup 1.0000x reference)
//
#include <hip/hip_runtime.h>
#include <hip/hip_bf16.h>

#define NPIX 4096
#define CIN  256
#define HID  512
#define QROWS 1536
#define NB   16

typedef unsigned int u32;
typedef unsigned short u16;
typedef float f32x4 __attribute__((ext_vector_type(4)));
typedef short bf16x8 __attribute__((ext_vector_type(8)));

__device__ __forceinline__ float bf2f(u16 u){
  union { u32 i; float f; } v; v.i = ((u32)u) << 16; return v.f;
}
__device__ __forceinline__ u16 f2bf(float f){
  union { float f; u32 u; } v; v.f = f;
  u32 r = v.u + 0x7fffu + ((v.u >> 16) & 1u);
  return (u16)(r >> 16);
}
__device__ __forceinline__ u32 pkbf(float a, float b){
  __hip_bfloat162 h = __float22bfloat162_rn(make_float2(a, b));
  union { __hip_bfloat162 h; u32 u; } cv; cv.h = h; return cv.u;
}
// async global(16B/lane) -> LDS (wave-uniform base + lane*16)
__device__ __forceinline__ void gload16(const u16* g, u16* l){
  __builtin_amdgcn_global_load_lds(
      (const __attribute__((address_space(1))) void*)g,
      (__attribute__((address_space(3))) void*)l, 16, 0, 0);
}

// Diagnostic: marker if workspace too small
__global__ void k_marker(float* y, int n){
  int i = blockIdx.x * 256 + threadIdx.x;
  if (i < n) y[i] = 1.0e6f;
}

// generic fp32 -> bf16 (8 elems/thread)
__global__ __launch_bounds__(256) void k_cvt(const float* __restrict__ src,
                                             u16* __restrict__ dst){
  const int i = (blockIdx.x * 256 + threadIdx.x) * 8;
  const float4 a = *(const float4*)(src + i);
  const float4 b = *(const float4*)(src + i + 4);
  *(uint4*)(dst + i) = make_uint4(pkbf(a.x,a.y), pkbf(a.z,a.w),
                                  pkbf(b.x,b.y), pkbf(b.z,b.w));
}

// ---------------------------------------------------------------------------
// K0: Xt[b][n][c] = bf16(X[b][c][n]) — transpose+convert pre-pass.
// ---------------------------------------------------------------------------
__global__ __launch_bounds__(256) void k_xt(const float* __restrict__ X,
                                            u16* __restrict__ Xt){
  __shared__ float ls[64][67];
  const int n0 = blockIdx.x * 64, c0 = blockIdx.y * 64, b = blockIdx.z;
  const int tid = threadIdx.x;
  const float* Xb = X + (size_t)b * CIN * NPIX;

  {
    const int r = tid >> 2, cq = (tid & 3) * 16;
    #pragma unroll
    for (int j = 0; j < 4; ++j)
      *(float4*)&ls[r][cq + j*4] = *(const float4*)&Xb[(size_t)(c0 + r) * NPIX + n0 + cq + j*4];
  }
  __syncthreads();
  {
    const int nr = tid >> 2, cs = (tid & 3) * 16;
    u32 pk[8];
    #pragma unroll
    for (int j = 0; j < 8; ++j)
      pk[j] = pkbf(ls[cs + 2*j][nr], ls[cs + 2*j + 1][nr]);
    u16* dst = Xt + (size_t)b * NPIX * CIN + (size_t)(n0 + nr) * CIN + c0 + cs;
    *(uint4*)(dst)     = make_uint4(pk[0], pk[1], pk[2], pk[3]);
    *(uint4*)(dst + 8) = make_uint4(pk[4], pk[5], pk[6], pk[7]);
  }
}

// ---------------------------------------------------------------------------
// K1 (MFMA, 2-phase counted-vmcnt): C[n][o] = Xt(n x c) . Wq(o x c).
// 128n x 128o tile, K=256 in 4 BK=64 stages. Double-buffered LDS (2x32KB).
// Pipeline: ISSUE stage(s+1) gload_lds BEFORE compute(s); raw s_barrier +
// asm s_waitcnt vmcnt(8) keeps next-stage loads in flight across the
// barrier (T3+T4; m218 counted-vs-drain = +38-73%). sched_barrier(0)
// pins ds_reads after the wait (rule #18). vmcnt arithmetic: 8 gload16
// per thread per stage; at wait, 8 new + 8 old outstanding -> vmcnt(8)
// retires exactly the old. Epilogue pool aliases buffer 0.
// ---------------------------------------------------------------------------
__global__ __launch_bounds__(256, 2) void k_qkv(
    const u16* __restrict__ Wq, const u16* __restrict__ Xt, u16* __restrict__ QKV)
{
  __shared__ __align__(16) u16 lds[32768];     // 65,536 B = 2 x (As 16KB + Bs 16KB)

  const int flat = blockIdx.x;                  // 0..6143 (= 8*768)
  const int virt = (flat & 7) * 768 + (flat >> 3);
  const int o0 = (virt % 12) * 128;
  const int n0 = ((virt / 12) & 31) * 128;
  const int b  = virt / 384;

  const int tid = threadIdx.x;
  const int lane = tid & 63;
  const int wv = tid >> 6;             // 4 waves
  const int wr = wv >> 1, wc = wv & 1; // wave tile: n-rows wr*64, o-cols wc*64
  const int g  = lane >> 4;            // k-octet group
  const int c  = lane & 15;            // row/col within fragment
  const u16* Xb = Xt + (size_t)b * NPIX * CIN;

  const int grow = lane >> 3;          // 0..7
  const int gch  = (lane & 7) * 8;     // k offset

  f32x4 acc[4][4];
  #pragma unroll
  for (int i = 0; i < 4; ++i)
    #pragma unroll
    for (int j = 0; j < 4; ++j) acc[i][j] = (f32x4){0.f, 0.f, 0.f, 0.f};

  // ---- prologue: stage buffer 0 with K-step 0 ----
  {
    u16* As = lds;
    u16* Bs = lds + 8192;
    #pragma unroll
    for (int i = 0; i < 4; ++i) {
      const int j = wv * 4 + i;
      const int row = j * 8 + grow;
      gload16(&Xb[(size_t)(n0 + row) * CIN + gch], &As[j * 512]);
      gload16(&Wq[(size_t)(o0 + row) * CIN + gch], &Bs[j * 512]);
    }
  }

  #pragma unroll
  for (int s = 0; s < 4; ++s) {
    const int cur = s & 1;
    // ---- ISSUE stage s+1 into the other buffer (stays in flight) ----
    if (s < 3) {
      const int k0 = (s + 1) * 64;
      u16* As = lds + (cur ^ 1) * 16384;
      u16* Bs = As + 8192;
      #pragma unroll
      for (int i = 0; i < 4; ++i) {
        const int j = wv * 4 + i;
        const int row = j * 8 + grow;
        gload16(&Xb[(size_t)(n0 + row) * CIN + k0 + gch], &As[j * 512]);
        gload16(&Wq[(size_t)(o0 + row) * CIN + k0 + gch], &Bs[j * 512]);
      }
      asm volatile("s_waitcnt vmcnt(8)" ::: "memory");
    } else {
      asm volatile("s_waitcnt vmcnt(0)" ::: "memory");
    }
    __builtin_amdgcn_s_barrier();
    __builtin_amdgcn_sched_barrier(0);

    // ---- COMPUTE from buf[cur]: 2 k-steps of 32 ----
    const u16* As = lds + cur * 16384;
    const u16* Bs = As + 8192;
    #pragma unroll
    for (int ks = 0; ks < 2; ++ks) {
      bf16x8 af[4], bfr[4];
      #pragma unroll
      for (int mf = 0; mf < 4; ++mf)
        af[mf] = *(const bf16x8*)&As[(wr * 64 + mf * 16 + c) * 64 + ks * 32 + g * 8];
      #pragma unroll
      for (int nf = 0; nf < 4; ++nf)
        bfr[nf] = *(const bf16x8*)&Bs[(wc * 64 + nf * 16 + c) * 64 + ks * 32 + g * 8];
      #pragma unroll
      for (int mf = 0; mf < 4; ++mf)
        #pragma unroll
        for (int nf = 0; nf < 4; ++nf)
          acc[mf][nf] = __builtin_amdgcn_mfma_f32_16x16x32_bf16(
              af[mf], bfr[nf], acc[mf][nf], 0, 0, 0);
    }
    __builtin_amdgcn_s_barrier();   // all waves done reading buf[cur]
  }

  // ---- epilogue: scatter into pool[o(128)][n(128)+pad8] (aliases lds) ----
  u16* pool = lds;
  #pragma unroll
  for (int mf = 0; mf < 4; ++mf) {
    const int nrow = wr * 64 + mf * 16 + g * 4;
    #pragma unroll
    for (int nf = 0; nf < 4; ++nf) {
      const int ocol = wc * 64 + nf * 16 + c;
      #pragma unroll
      for (int r = 0; r < 4; ++r)
        pool[ocol * 136 + nrow + r] = f2bf(acc[mf][nf][r]);
    }
  }
  __syncthreads();
  u16* dst = QKV + (size_t)b * QROWS * NPIX;
  #pragma unroll
  for (int i = 0; i < 8; ++i) {
    const int f2 = i * 256 + tid;
    const int orow = f2 >> 4, ch = f2 & 15;   // 128 rows x 16 16B-chunks
    const uint4 v = *(const uint4*)&pool[orow * 136 + ch * 8];
    *(uint4*)&dst[(size_t)(o0 + orow) * NPIX + n0 + ch * 8] = v;
  }
}

// ---------------------------------------------------------------------------
// K3 (MFMA, no-max softmax): ctxp[split][b,h,d,e] = sum_{n in split}
// exp(k[d,n]) * v[e,n]  (UNNORMALIZED), plus Sp[split][b,h,d] = sum exp.
// ---------------------------------------------------------------------------
__global__ __launch_bounds__(256) void k_ctx(const u16* __restrict__ QKV,
    float* __restrict__ ctxp, float* __restrict__ Sp)
{
  __shared__ __align__(16) u16 ks[64 * 72];   // 9,216 B
  __shared__ __align__(16) u16 vs[64 * 72];   // 9,216 B
  const int split = blockIdx.x, h = blockIdx.y, b = blockIdx.z;
  const int tid = threadIdx.x;
  const int lane = tid & 63, wv = tid >> 6;
  const int g = lane >> 4, c = lane & 15;
  const u16* kb = QKV + ((size_t)b * QROWS + HID     + h * 64) * NPIX;
  const u16* vb = QKV + ((size_t)b * QROWS + 2 * HID + h * 64) * NPIX;

  const int srow = tid >> 2;          // staging row 0..63 (4 thr/row)
  const int sch  = (tid & 3) * 16;    // staging n-chunk

  f32x4 acc[4];
  #pragma unroll
  for (int j = 0; j < 4; ++j) acc[j] = (f32x4){0.f, 0.f, 0.f, 0.f};
  float s_part = 0.f;

  for (int t = 0; t < 16; ++t) {
    const int n0 = split * 1024 + t * 64;
    {
      const uint4 r0 = *(const uint4*)(kb + (size_t)srow * NPIX + n0 + sch);
      const uint4 r1 = *(const uint4*)(kb + (size_t)srow * NPIX + n0 + sch + 8);
      const u32 w[8] = {r0.x, r0.y, r0.z, r0.w, r1.x, r1.y, r1.z, r1.w};
      u32 pk[8];
      #pragma unroll
      for (int j = 0; j < 8; ++j) {
        const float lo = __expf(bf2f((u16)(w[j] & 0xffff)));
        const float hi = __expf(bf2f((u16)(w[j] >> 16)));
        s_part += lo + hi;
        pk[j] = pkbf(lo, hi);
      }
      *(uint4*)&ks[srow * 72 + sch]     = make_uint4(pk[0], pk[1], pk[2], pk[3]);
      *(uint4*)&ks[srow * 72 + sch + 8] = make_uint4(pk[4], pk[5], pk[6], pk[7]);
      const uint4 v0 = *(const uint4*)(vb + (size_t)srow * NPIX + n0 + sch);
      const uint4 v1 = *(const uint4*)(vb + (size_t)srow * NPIX + n0 + sch + 8);
      *(uint4*)&vs[srow * 72 + sch]     = v0;
      *(uint4*)&vs[srow * 72 + sch + 8] = v1;
    }
    __syncthreads();
    #pragma unroll
    for (int ks2 = 0; ks2 < 2; ++ks2) {
      const bf16x8 af = *(const bf16x8*)&ks[(wv * 16 + c) * 72 + ks2 * 32 + g * 8];
      #pragma unroll
      for (int nf = 0; nf < 4; ++nf) {
        const bf16x8 bf = *(const bf16x8*)&vs[(nf * 16 + c) * 72 + ks2 * 32 + g * 8];
        acc[nf] = __builtin_amdgcn_mfma_f32_16x16x32_bf16(af, bf, acc[nf], 0, 0, 0);
      }
    }
    __syncthreads();
  }
  s_part += __shfl_xor(s_part, 1, 64);
  s_part += __shfl_xor(s_part, 2, 64);
  if ((tid & 3) == 0)
    Sp[(size_t)split * 8192 + (b * 8 + h) * 64 + srow] = s_part;

  float* dst = ctxp + (size_t)split * (NB*8*64*64) + ((size_t)(b*8+h)) * 4096;
  #pragma unroll
  for (int nf = 0; nf < 4; ++nf)
    #pragma unroll
    for (int r = 0; r < 4; ++r)
      dst[(wv*16 + g*4 + r) * 64 + nf*16 + c] = acc[nf][r];
}

// K3b: reduce 4 partials + normalize by S (deferred softmax denominator)
__global__ __launch_bounds__(256) void k_ctxred(const float* __restrict__ ctxp,
                                                const float* __restrict__ Sp,
                                                float* __restrict__ ctx)
{
  const int SZ = NB*8*64*64;  // 524288
  const int i = (blockIdx.x * 256 + threadIdx.x) * 4;
  const int bh = i >> 12, d = (i >> 6) & 63;
  const int si = bh * 64 + d;
  const float S = Sp[si] + Sp[8192 + si] + Sp[16384 + si] + Sp[24576 + si];
  const float inv = 1.0f / S;
  float4 a  = *(const float4*)(ctxp + i);
  const float4 c1 = *(const float4*)(ctxp + SZ   + i);
  const float4 c2 = *(const float4*)(ctxp + 2*SZ + i);
  const float4 c3 = *(const float4*)(ctxp + 3*SZ + i);
  a.x = (a.x + c1.x + c2.x + c3.x) * inv;
  a.y = (a.y + c1.y + c2.y + c3.y) * inv;
  a.z = (a.z + c1.z + c2.z + c3.z) * inv;
  a.w = (a.w + c1.w + c2.w + c3.w) * inv;
  *(float4*)(ctx + i) = a;
}

// ---------------------------------------------------------------------------
// K4 (MFMA): out[e,n] = sum_d ctx[d,e]*q'[d,n], q' = softmax_d(q)*0.125.
// C[n][e] = q'(n x d) . ctxT(e x d). Thread-local softmax (d=64 in regs).
// ---------------------------------------------------------------------------
__global__ __launch_bounds__(256) void k_qctx(u16* __restrict__ QKV,
    const float* __restrict__ ctx)
{
  __shared__ __align__(16) u16 As[256 * 72];   // 36,864 B  (q'[n][d])
  __shared__ __align__(16) u16 Bs[64 * 72];    //  9,216 B  (ctxT[e][d])
  const int nt = blockIdx.x, h = blockIdx.y, b = blockIdx.z;
  const int n0 = nt * 256;
  const int tid = threadIdx.x;
  const int lane = tid & 63, wv = tid >> 6;
  const int g = lane >> 4, c = lane & 15;

  const float* cbase = ctx + ((size_t)(b*8+h)) * 4096;
  #pragma unroll
  for (int j = 0; j < 16; ++j) {
    const int idx = tid + j * 256;      // coalesced f32 read
    const int d = idx >> 6, e = idx & 63;
    Bs[e * 72 + d] = f2bf(cbase[idx]);
  }

  const u16* qb = QKV + ((size_t)b*QROWS + h*64) * NPIX;
  float vals[64];
  float mx = -3.0e38f;
  #pragma unroll
  for (int d = 0; d < 64; ++d) {
    vals[d] = bf2f(qb[(size_t)d * NPIX + n0 + tid]);
    mx = fmaxf(mx, vals[d]);
  }
  float s = 0.f;
  #pragma unroll
  for (int d = 0; d < 64; ++d) { vals[d] = __expf(vals[d] - mx); s += vals[d]; }
  const float sc = 0.125f / s;
  #pragma unroll
  for (int q = 0; q < 8; ++q) {
    u32 pk[4];
    #pragma unroll
    for (int p = 0; p < 4; ++p)
      pk[p] = pkbf(vals[q*8 + 2*p] * sc, vals[q*8 + 2*p + 1] * sc);
    *(uint4*)&As[tid * 72 + q * 8] = make_uint4(pk[0], pk[1], pk[2], pk[3]);
  }
  __syncthreads();

  f32x4 acc[4][4];
  #pragma unroll
  for (int i = 0; i < 4; ++i)
    #pragma unroll
    for (int j = 0; j < 4; ++j) acc[i][j] = (f32x4){0.f, 0.f, 0.f, 0.f};
  #pragma unroll
  for (int ks = 0; ks < 2; ++ks) {
    bf16x8 af[4], bfr[4];
    #pragma unroll
    for (int mf = 0; mf < 4; ++mf)
      af[mf] = *(const bf16x8*)&As[(wv * 64 + mf * 16 + c) * 72 + ks * 32 + g * 8];
    #pragma unroll
    for (int nf = 0; nf < 4; ++nf)
      bfr[nf] = *(const bf16x8*)&Bs[(nf * 16 + c) * 72 + ks * 32 + g * 8];
    #pragma unroll
    for (int mf = 0; mf < 4; ++mf)
      #pragma unroll
      for (int nf = 0; nf < 4; ++nf)
        acc[mf][nf] = __builtin_amdgcn_mfma_f32_16x16x32_bf16(
            af[mf], bfr[nf], acc[mf][nf], 0, 0, 0);
  }
  __syncthreads();

  u16* pool = As;   // 64*264 = 16,896 u16 <= 18,432 u16 of As
  #pragma unroll
  for (int mf = 0; mf < 4; ++mf) {
    const int nrow = wv * 64 + mf * 16 + g * 4;
    #pragma unroll
    for (int nf = 0; nf < 4; ++nf) {
      const int ecol = nf * 16 + c;
      #pragma unroll
      for (int r = 0; r < 4; ++r)
        pool[ecol * 264 + nrow + r] = f2bf(acc[mf][nf][r]);
    }
  }
  __syncthreads();
  u16* ob = QKV + ((size_t)b*QROWS + h*64) * NPIX;   // aliased out
  #pragma unroll
  for (int i = 0; i < 8; ++i) {
    const int f2 = i * 256 + tid;
    const int erow = f2 >> 5, ch = f2 & 31;   // 64 rows x 32 16B-chunks
    const uint4 v = *(const uint4*)&pool[erow * 264 + ch * 8];
    *(uint4*)&ob[(size_t)erow * NPIX + n0 + ch * 8] = v;
  }
}

// ---------------------------------------------------------------------------
// K5 (MFMA): y[c,n] = sum_e Wo[c,e]*out[e,n] + bo[c]; L2-norm over c; *g*8
// ---------------------------------------------------------------------------
__global__ __launch_bounds__(256) void k_proj(const u16* __restrict__ QKV,
    const u16* __restrict__ Wbf, const float* __restrict__ bo,
    const float* __restrict__ gg, float* __restrict__ Y)
{
  __shared__ __align__(16) u16 As[256][72];   // 36,864 B
  __shared__ __align__(16) u16 Bs[64][72];    //  9,216 B
  __shared__ float red[4][64];
  __shared__ float sbias[256], sgain[256];
  const int nt = blockIdx.x, b = blockIdx.y;
  const int n0 = nt * 64;
  const int tid = threadIdx.x;
  const int lane = tid & 63, wv = tid >> 6;
  const int g = lane >> 4, c = lane & 15;
  const u16* ob = QKV + (size_t)b * QROWS * NPIX;   // aliased out (bf16)

  sbias[tid] = bo[tid];
  sgain[tid] = gg[tid];

  f32x4 acc[4][4];
  #pragma unroll
  for (int i = 0; i < 4; ++i)
    #pragma unroll
    for (int j = 0; j < 4; ++j) acc[i][j] = (f32x4){0.f, 0.f, 0.f, 0.f};

  for (int s = 0; s < 8; ++s) {
    const int k0 = s * 64;
    #pragma unroll
    for (int i = 0; i < 8; ++i) {
      const int flat = i * 256 + tid;
      const int row = flat >> 3, kc = flat & 7;
      *(uint4*)&As[row][kc * 8] =
          *(const uint4*)&Wbf[(size_t)row * HID + k0 + kc * 8];
    }
    {
      const int kb0 = wv * 16;
      u16 vals[16];
      #pragma unroll
      for (int kk = 0; kk < 16; ++kk)
        vals[kk] = ob[(size_t)(k0 + kb0 + kk) * NPIX + n0 + lane];
      u32 pk[8];
      #pragma unroll
      for (int j = 0; j < 8; ++j)
        pk[j] = (u32)vals[2*j] | ((u32)vals[2*j+1] << 16);
      *(uint4*)&Bs[lane][kb0]     = make_uint4(pk[0], pk[1], pk[2], pk[3]);
      *(uint4*)&Bs[lane][kb0 + 8] = make_uint4(pk[4], pk[5], pk[6], pk[7]);
    }
    __syncthreads();

    #pragma unroll
    for (int ks = 0; ks < 2; ++ks) {
      bf16x8 af[4], bfr[4];
      #pragma unroll
      for (int mf = 0; mf < 4; ++mf)
        af[mf] = *(const bf16x8*)&As[wv * 64 + mf * 16 + c][ks * 32 + g * 8];
      #pragma unroll
      for (int nf = 0; nf < 4; ++nf)
        bfr[nf] = *(const bf16x8*)&Bs[nf * 16 + c][ks * 32 + g * 8];
      #pragma unroll
      for (int mf = 0; mf < 4; ++mf)
        #pragma unroll
        for (int nf = 0; nf < 4; ++nf)
          acc[mf][nf] = __builtin_amdgcn_mfma_f32_16x16x32_bf16(
              af[mf], bfr[nf], acc[mf][nf], 0, 0, 0);
    }
    __syncthreads();
  }

  #pragma unroll
  for (int mf = 0; mf < 4; ++mf)
    #pragma unroll
    for (int r = 0; r < 4; ++r) {
      const float bb = sbias[wv * 64 + mf * 16 + g * 4 + r];
      #pragma unroll
      for (int nf = 0; nf < 4; ++nf) acc[mf][nf][r] += bb;
    }

  #pragma unroll
  for (int nf = 0; nf < 4; ++nf) {
    float v = 0.f;
    #pragma unroll
    for (int mf = 0; mf < 4; ++mf)
      #pragma unroll
      for (int r = 0; r < 4; ++r)
        v = fmaf(acc[mf][nf][r], acc[mf][nf][r], v);
    v += __shfl_xor(v, 16, 64);   // reduce over g
    v += __shfl_xor(v, 32, 64);
    if (g == 0) red[wv][nf * 16 + c] = v;
  }
  __syncthreads();
  float scale[4];
  #pragma unroll
  for (int nf = 0; nf < 4; ++nf) {
    const int col = nf * 16 + c;
    const float tot = red[0][col] + red[1][col] + red[2][col] + red[3][col];
    scale[nf] = 8.0f / fmaxf(sqrtf(tot), 1e-12f);
  }

  float* yb = Y + (size_t)b * CIN * NPIX;
  #pragma unroll
  for (int mf = 0; mf < 4; ++mf)
    #pragma unroll
    for (int r = 0; r < 4; ++r) {
      const int row = wv * 64 + mf * 16 + g * 4 + r;
      const float gr = sgain[row];
      #pragma unroll
      for (int nf = 0; nf < 4; ++nf)
        yb[(size_t)row * NPIX + n0 + nf * 16 + c] = acc[mf][nf][r] * scale[nf] * gr;
    }
}

extern "C" void kernel_launch(void* const* d_in, const int* in_sizes, int n_in,
                              void* d_out, int out_size, void* d_ws, size_t ws_size,
                              hipStream_t stream) {
  const float* x     = (const float*)d_in[0];
  const float* w_qkv = (const float*)d_in[1];
  const float* w_out = (const float*)d_in[2];
  const float* b_out = (const float*)d_in[3];
  const float* g     = (const float*)d_in[4];
  float* y = (float*)d_out;

  char* ws = (char*)d_ws;
  // layout (bytes):
  //   qkv  bf16 : 16*1536*4096*2 = 201,326,592   (q-section reused as `out`)
  //   xt   bf16 : 16*4096*256*2  =  33,554,432   at 201,326,592
  //     (xt is DEAD after k_qkv; ctx/ctxp/Sp alias into its window,
  //      all written strictly after k_qkv in stream order)
  //   ctx   f32 : alias 201,392,128 (2,097,152)
  //   ctxp  f32 : alias 203,489,280 (8,388,608)
  //   Sp    f32 : alias 211,877,888 (131,072)
  //   wbf  bf16 : 234,881,024 (262,144)
  //   wqb  bf16 : 235,143,168 (786,432)
  //   total     = 235,929,600
  u16*    qkv   = (u16*)(ws);
  u16*    xt    = (u16*)(ws + 201326592);
  float*  ctx   = (float*)(ws + 201392128);
  float*  ctxp  = (float*)(ws + 203489280);
  float*  Sp    = (float*)(ws + 211877888);
  u16*    wbf   = (u16*)(ws + 234881024);
  u16*    wqb   = (u16*)(ws + 235143168);

  if (ws_size < 235929600) {
    // diagnostic marker: if this shows up as absmax ~1e6, ws_size too small
    k_marker<<<dim3((out_size + 255) / 256), 256, 0, stream>>>(y, out_size);
    return;
  }

  k_cvt   <<<dim3(64),         256, 0, stream>>>(w_out, wbf);
  k_cvt   <<<dim3(192),        256, 0, stream>>>(w_qkv, wqb);
  k_xt    <<<dim3(64, 4, 16),  256, 0, stream>>>(x, xt);
  k_qkv   <<<dim3(6144),       256, 0, stream>>>(wqb, xt, qkv);
  k_ctx   <<<dim3(4, 8, 16),   256, 0, stream>>>(qkv, ctxp, Sp);
  k_ctxred<<<dim3(512),        256, 0, stream>>>(ctxp, Sp, ctx);
  k_qctx  <<<dim3(16, 8, 16),  256, 0, stream>>>(qkv, ctx);
  k_proj  <<<dim3(64, 16),     256, 0, stream>>>(qkv, wbf, b_out, g, y);
}

// Round 18
// 198.776 us; speedup vs baseline: 1.0010x; 1.0010x over previous
//
#include <hip/hip_runtime.h>
#include <hip/hip_bf16.h>

#define NPIX 4096
#define CIN  256
#define HID  512
#define QROWS 1536
#define NB   16

typedef unsigned int u32;
typedef unsigned short u16;
typedef float f32x4 __attribute__((ext_vector_type(4)));
typedef short bf16x8 __attribute__((ext_vector_type(8)));

__device__ __forceinline__ float bf2f(u16 u){
  union { u32 i; float f; } v; v.i = ((u32)u) << 16; return v.f;
}
__device__ __forceinline__ u16 f2bf(float f){
  union { float f; u32 u; } v; v.f = f;
  u32 r = v.u + 0x7fffu + ((v.u >> 16) & 1u);
  return (u16)(r >> 16);
}
__device__ __forceinline__ u32 pkbf(float a, float b){
  __hip_bfloat162 h = __float22bfloat162_rn(make_float2(a, b));
  union { __hip_bfloat162 h; u32 u; } cv; cv.h = h; return cv.u;
}
// async global(16B/lane) -> LDS (wave-uniform base + lane*16)
__device__ __forceinline__ void gload16(const u16* g, u16* l){
  __builtin_amdgcn_global_load_lds(
      (const __attribute__((address_space(1))) void*)g,
      (__attribute__((address_space(3))) void*)l, 16, 0, 0);
}

// Diagnostic: marker if workspace too small
__global__ void k_marker(float* y, int n){
  int i = blockIdx.x * 256 + threadIdx.x;
  if (i < n) y[i] = 1.0e6f;
}

// generic fp32 -> bf16 (8 elems/thread)
__global__ __launch_bounds__(256) void k_cvt(const float* __restrict__ src,
                                             u16* __restrict__ dst){
  const int i = (blockIdx.x * 256 + threadIdx.x) * 8;
  const float4 a = *(const float4*)(src + i);
  const float4 b = *(const float4*)(src + i + 4);
  *(uint4*)(dst + i) = make_uint4(pkbf(a.x,a.y), pkbf(a.z,a.w),
                                  pkbf(b.x,b.y), pkbf(b.z,b.w));
}

// ---------------------------------------------------------------------------
// K0: Xt[b][n][c] = bf16(X[b][c][n]) — transpose+convert pre-pass.
// ---------------------------------------------------------------------------
__global__ __launch_bounds__(256) void k_xt(const float* __restrict__ X,
                                            u16* __restrict__ Xt){
  __shared__ float ls[64][67];
  const int n0 = blockIdx.x * 64, c0 = blockIdx.y * 64, b = blockIdx.z;
  const int tid = threadIdx.x;
  const float* Xb = X + (size_t)b * CIN * NPIX;

  {
    const int r = tid >> 2, cq = (tid & 3) * 16;
    #pragma unroll
    for (int j = 0; j < 4; ++j)
      *(float4*)&ls[r][cq + j*4] = *(const float4*)&Xb[(size_t)(c0 + r) * NPIX + n0 + cq + j*4];
  }
  __syncthreads();
  {
    const int nr = tid >> 2, cs = (tid & 3) * 16;
    u32 pk[8];
    #pragma unroll
    for (int j = 0; j < 8; ++j)
      pk[j] = pkbf(ls[cs + 2*j][nr], ls[cs + 2*j + 1][nr]);
    u16* dst = Xt + (size_t)b * NPIX * CIN + (size_t)(n0 + nr) * CIN + c0 + cs;
    *(uint4*)(dst)     = make_uint4(pk[0], pk[1], pk[2], pk[3]);
    *(uint4*)(dst + 8) = make_uint4(pk[4], pk[5], pk[6], pk[7]);
  }
}

// ---------------------------------------------------------------------------
// K1 (MFMA, 2-phase counted-vmcnt): C[n][o] = Xt(n x c) . Wq(o x c).
// 128n x 128o tile, K=256 in 4 BK=64 stages. Double-buffered LDS (2x32KB).
// Pipeline: ISSUE stage(s+1) gload_lds BEFORE compute(s); raw s_barrier +
// asm s_waitcnt vmcnt(8) keeps next-stage loads in flight across the
// barrier (T3+T4; m218 counted-vs-drain = +38-73%). sched_barrier(0)
// pins ds_reads after the wait (rule #18). vmcnt arithmetic: 8 gload16
// per thread per stage; at wait, 8 new + 8 old outstanding -> vmcnt(8)
// retires exactly the old. Epilogue pool aliases buffer 0.
// ---------------------------------------------------------------------------
__global__ __launch_bounds__(256, 2) void k_qkv(
    const u16* __restrict__ Wq, const u16* __restrict__ Xt, u16* __restrict__ QKV)
{
  __shared__ __align__(16) u16 lds[32768];     // 65,536 B = 2 x (As 16KB + Bs 16KB)

  const int flat = blockIdx.x;                  // 0..6143 (= 8*768)
  const int virt = (flat & 7) * 768 + (flat >> 3);
  const int o0 = (virt % 12) * 128;
  const int n0 = ((virt / 12) & 31) * 128;
  const int b  = virt / 384;

  const int tid = threadIdx.x;
  const int lane = tid & 63;
  const int wv = tid >> 6;             // 4 waves
  const int wr = wv >> 1, wc = wv & 1; // wave tile: n-rows wr*64, o-cols wc*64
  const int g  = lane >> 4;            // k-octet group
  const int c  = lane & 15;            // row/col within fragment
  const u16* Xb = Xt + (size_t)b * NPIX * CIN;

  const int grow = lane >> 3;          // 0..7
  const int gch  = (lane & 7) * 8;     // k offset

  f32x4 acc[4][4];
  #pragma unroll
  for (int i = 0; i < 4; ++i)
    #pragma unroll
    for (int j = 0; j < 4; ++j) acc[i][j] = (f32x4){0.f, 0.f, 0.f, 0.f};

  // ---- prologue: stage buffer 0 with K-step 0 ----
  {
    u16* As = lds;
    u16* Bs = lds + 8192;
    #pragma unroll
    for (int i = 0; i < 4; ++i) {
      const int j = wv * 4 + i;
      const int row = j * 8 + grow;
      gload16(&Xb[(size_t)(n0 + row) * CIN + gch], &As[j * 512]);
      gload16(&Wq[(size_t)(o0 + row) * CIN + gch], &Bs[j * 512]);
    }
  }

  #pragma unroll
  for (int s = 0; s < 4; ++s) {
    const int cur = s & 1;
    // ---- ISSUE stage s+1 into the other buffer (stays in flight) ----
    if (s < 3) {
      const int k0 = (s + 1) * 64;
      u16* As = lds + (cur ^ 1) * 16384;
      u16* Bs = As + 8192;
      #pragma unroll
      for (int i = 0; i < 4; ++i) {
        const int j = wv * 4 + i;
        const int row = j * 8 + grow;
        gload16(&Xb[(size_t)(n0 + row) * CIN + k0 + gch], &As[j * 512]);
        gload16(&Wq[(size_t)(o0 + row) * CIN + k0 + gch], &Bs[j * 512]);
      }
      asm volatile("s_waitcnt vmcnt(8)" ::: "memory");
    } else {
      asm volatile("s_waitcnt vmcnt(0)" ::: "memory");
    }
    __builtin_amdgcn_s_barrier();
    __builtin_amdgcn_sched_barrier(0);

    // ---- COMPUTE from buf[cur]: 2 k-steps of 32 ----
    const u16* As = lds + cur * 16384;
    const u16* Bs = As + 8192;
    #pragma unroll
    for (int ks = 0; ks < 2; ++ks) {
      bf16x8 af[4], bfr[4];
      #pragma unroll
      for (int mf = 0; mf < 4; ++mf)
        af[mf] = *(const bf16x8*)&As[(wr * 64 + mf * 16 + c) * 64 + ks * 32 + g * 8];
      #pragma unroll
      for (int nf = 0; nf < 4; ++nf)
        bfr[nf] = *(const bf16x8*)&Bs[(wc * 64 + nf * 16 + c) * 64 + ks * 32 + g * 8];
      #pragma unroll
      for (int mf = 0; mf < 4; ++mf)
        #pragma unroll
        for (int nf = 0; nf < 4; ++nf)
          acc[mf][nf] = __builtin_amdgcn_mfma_f32_16x16x32_bf16(
              af[mf], bfr[nf], acc[mf][nf], 0, 0, 0);
    }
    __builtin_amdgcn_s_barrier();   // all waves done reading buf[cur]
  }

  // ---- epilogue: scatter into pool[o(128)][n(128)+pad8] (aliases lds) ----
  u16* pool = lds;
  #pragma unroll
  for (int mf = 0; mf < 4; ++mf) {
    const int nrow = wr * 64 + mf * 16 + g * 4;
    #pragma unroll
    for (int nf = 0; nf < 4; ++nf) {
      const int ocol = wc * 64 + nf * 16 + c;
      #pragma unroll
      for (int r = 0; r < 4; ++r)
        pool[ocol * 136 + nrow + r] = f2bf(acc[mf][nf][r]);
    }
  }
  __syncthreads();
  u16* dst = QKV + (size_t)b * QROWS * NPIX;
  #pragma unroll
  for (int i = 0; i < 8; ++i) {
    const int f2 = i * 256 + tid;
    const int orow = f2 >> 4, ch = f2 & 15;   // 128 rows x 16 16B-chunks
    const uint4 v = *(const uint4*)&pool[orow * 136 + ch * 8];
    *(uint4*)&dst[(size_t)(o0 + orow) * NPIX + n0 + ch * 8] = v;
  }
}

// ---------------------------------------------------------------------------
// K3 (MFMA, no-max softmax): ctxp[split][b,h,d,e] = sum_{n in split}
// exp(k[d,n]) * v[e,n]  (UNNORMALIZED), plus Sp[split][b,h,d] = sum exp.
// ---------------------------------------------------------------------------
__global__ __launch_bounds__(256) void k_ctx(const u16* __restrict__ QKV,
    float* __restrict__ ctxp, float* __restrict__ Sp)
{
  __shared__ __align__(16) u16 ks[64 * 72];   // 9,216 B
  __shared__ __align__(16) u16 vs[64 * 72];   // 9,216 B
  const int split = blockIdx.x, h = blockIdx.y, b = blockIdx.z;
  const int tid = threadIdx.x;
  const int lane = tid & 63, wv = tid >> 6;
  const int g = lane >> 4, c = lane & 15;
  const u16* kb = QKV + ((size_t)b * QROWS + HID     + h * 64) * NPIX;
  const u16* vb = QKV + ((size_t)b * QROWS + 2 * HID + h * 64) * NPIX;

  const int srow = tid >> 2;          // staging row 0..63 (4 thr/row)
  const int sch  = (tid & 3) * 16;    // staging n-chunk

  f32x4 acc[4];
  #pragma unroll
  for (int j = 0; j < 4; ++j) acc[j] = (f32x4){0.f, 0.f, 0.f, 0.f};
  float s_part = 0.f;

  for (int t = 0; t < 16; ++t) {
    const int n0 = split * 1024 + t * 64;
    {
      const uint4 r0 = *(const uint4*)(kb + (size_t)srow * NPIX + n0 + sch);
      const uint4 r1 = *(const uint4*)(kb + (size_t)srow * NPIX + n0 + sch + 8);
      const u32 w[8] = {r0.x, r0.y, r0.z, r0.w, r1.x, r1.y, r1.z, r1.w};
      u32 pk[8];
      #pragma unroll
      for (int j = 0; j < 8; ++j) {
        const float lo = __expf(bf2f((u16)(w[j] & 0xffff)));
        const float hi = __expf(bf2f((u16)(w[j] >> 16)));
        s_part += lo + hi;
        pk[j] = pkbf(lo, hi);
      }
      *(uint4*)&ks[srow * 72 + sch]     = make_uint4(pk[0], pk[1], pk[2], pk[3]);
      *(uint4*)&ks[srow * 72 + sch + 8] = make_uint4(pk[4], pk[5], pk[6], pk[7]);
      const uint4 v0 = *(const uint4*)(vb + (size_t)srow * NPIX + n0 + sch);
      const uint4 v1 = *(const uint4*)(vb + (size_t)srow * NPIX + n0 + sch + 8);
      *(uint4*)&vs[srow * 72 + sch]     = v0;
      *(uint4*)&vs[srow * 72 + sch + 8] = v1;
    }
    __syncthreads();
    #pragma unroll
    for (int ks2 = 0; ks2 < 2; ++ks2) {
      const bf16x8 af = *(const bf16x8*)&ks[(wv * 16 + c) * 72 + ks2 * 32 + g * 8];
      #pragma unroll
      for (int nf = 0; nf < 4; ++nf) {
        const bf16x8 bf = *(const bf16x8*)&vs[(nf * 16 + c) * 72 + ks2 * 32 + g * 8];
        acc[nf] = __builtin_amdgcn_mfma_f32_16x16x32_bf16(af, bf, acc[nf], 0, 0, 0);
      }
    }
    __syncthreads();
  }
  s_part += __shfl_xor(s_part, 1, 64);
  s_part += __shfl_xor(s_part, 2, 64);
  if ((tid & 3) == 0)
    Sp[(size_t)split * 8192 + (b * 8 + h) * 64 + srow] = s_part;

  float* dst = ctxp + (size_t)split * (NB*8*64*64) + ((size_t)(b*8+h)) * 4096;
  #pragma unroll
  for (int nf = 0; nf < 4; ++nf)
    #pragma unroll
    for (int r = 0; r < 4; ++r)
      dst[(wv*16 + g*4 + r) * 64 + nf*16 + c] = acc[nf][r];
}

// K3b: reduce 4 partials + normalize by S (deferred softmax denominator)
__global__ __launch_bounds__(256) void k_ctxred(const float* __restrict__ ctxp,
                                                const float* __restrict__ Sp,
                                                float* __restrict__ ctx)
{
  const int SZ = NB*8*64*64;  // 524288
  const int i = (blockIdx.x * 256 + threadIdx.x) * 4;
  const int bh = i >> 12, d = (i >> 6) & 63;
  const int si = bh * 64 + d;
  const float S = Sp[si] + Sp[8192 + si] + Sp[16384 + si] + Sp[24576 + si];
  const float inv = 1.0f / S;
  float4 a  = *(const float4*)(ctxp + i);
  const float4 c1 = *(const float4*)(ctxp + SZ   + i);
  const float4 c2 = *(const float4*)(ctxp + 2*SZ + i);
  const float4 c3 = *(const float4*)(ctxp + 3*SZ + i);
  a.x = (a.x + c1.x + c2.x + c3.x) * inv;
  a.y = (a.y + c1.y + c2.y + c3.y) * inv;
  a.z = (a.z + c1.z + c2.z + c3.z) * inv;
  a.w = (a.w + c1.w + c2.w + c3.w) * inv;
  *(float4*)(ctx + i) = a;
}

// ---------------------------------------------------------------------------
// K4 (MFMA): out[e,n] = sum_d ctx[d,e]*q'[d,n], q' = softmax_d(q)*0.125.
// C[n][e] = q'(n x d) . ctxT(e x d). Thread-local softmax (d=64 in regs).
// ---------------------------------------------------------------------------
__global__ __launch_bounds__(256) void k_qctx(u16* __restrict__ QKV,
    const float* __restrict__ ctx)
{
  __shared__ __align__(16) u16 As[256 * 72];   // 36,864 B  (q'[n][d])
  __shared__ __align__(16) u16 Bs[64 * 72];    //  9,216 B  (ctxT[e][d])
  const int nt = blockIdx.x, h = blockIdx.y, b = blockIdx.z;
  const int n0 = nt * 256;
  const int tid = threadIdx.x;
  const int lane = tid & 63, wv = tid >> 6;
  const int g = lane >> 4, c = lane & 15;

  const float* cbase = ctx + ((size_t)(b*8+h)) * 4096;
  #pragma unroll
  for (int j = 0; j < 16; ++j) {
    const int idx = tid + j * 256;      // coalesced f32 read
    const int d = idx >> 6, e = idx & 63;
    Bs[e * 72 + d] = f2bf(cbase[idx]);
  }

  const u16* qb = QKV + ((size_t)b*QROWS + h*64) * NPIX;
  float vals[64];
  float mx = -3.0e38f;
  #pragma unroll
  for (int d = 0; d < 64; ++d) {
    vals[d] = bf2f(qb[(size_t)d * NPIX + n0 + tid]);
    mx = fmaxf(mx, vals[d]);
  }
  float s = 0.f;
  #pragma unroll
  for (int d = 0; d < 64; ++d) { vals[d] = __expf(vals[d] - mx); s += vals[d]; }
  const float sc = 0.125f / s;
  #pragma unroll
  for (int q = 0; q < 8; ++q) {
    u32 pk[4];
    #pragma unroll
    for (int p = 0; p < 4; ++p)
      pk[p] = pkbf(vals[q*8 + 2*p] * sc, vals[q*8 + 2*p + 1] * sc);
    *(uint4*)&As[tid * 72 + q * 8] = make_uint4(pk[0], pk[1], pk[2], pk[3]);
  }
  __syncthreads();

  f32x4 acc[4][4];
  #pragma unroll
  for (int i = 0; i < 4; ++i)
    #pragma unroll
    for (int j = 0; j < 4; ++j) acc[i][j] = (f32x4){0.f, 0.f, 0.f, 0.f};
  #pragma unroll
  for (int ks = 0; ks < 2; ++ks) {
    bf16x8 af[4], bfr[4];
    #pragma unroll
    for (int mf = 0; mf < 4; ++mf)
      af[mf] = *(const bf16x8*)&As[(wv * 64 + mf * 16 + c) * 72 + ks * 32 + g * 8];
    #pragma unroll
    for (int nf = 0; nf < 4; ++nf)
      bfr[nf] = *(const bf16x8*)&Bs[(nf * 16 + c) * 72 + ks * 32 + g * 8];
    #pragma unroll
    for (int mf = 0; mf < 4; ++mf)
      #pragma unroll
      for (int nf = 0; nf < 4; ++nf)
        acc[mf][nf] = __builtin_amdgcn_mfma_f32_16x16x32_bf16(
            af[mf], bfr[nf], acc[mf][nf], 0, 0, 0);
  }
  __syncthreads();

  u16* pool = As;   // 64*264 = 16,896 u16 <= 18,432 u16 of As
  #pragma unroll
  for (int mf = 0; mf < 4; ++mf) {
    const int nrow = wv * 64 + mf * 16 + g * 4;
    #pragma unroll
    for (int nf = 0; nf < 4; ++nf) {
      const int ecol = nf * 16 + c;
      #pragma unroll
      for (int r = 0; r < 4; ++r)
        pool[ecol * 264 + nrow + r] = f2bf(acc[mf][nf][r]);
    }
  }
  __syncthreads();
  u16* ob = QKV + ((size_t)b*QROWS + h*64) * NPIX;   // aliased out
  #pragma unroll
  for (int i = 0; i < 8; ++i) {
    const int f2 = i * 256 + tid;
    const int erow = f2 >> 5, ch = f2 & 31;   // 64 rows x 32 16B-chunks
    const uint4 v = *(const uint4*)&pool[erow * 264 + ch * 8];
    *(uint4*)&ob[(size_t)erow * NPIX + n0 + ch * 8] = v;
  }
}

// ---------------------------------------------------------------------------
// K5 (MFMA): y[c,n] = sum_e Wo[c,e]*out[e,n] + bo[c]; L2-norm over c; *g*8
// ---------------------------------------------------------------------------
__global__ __launch_bounds__(256) void k_proj(const u16* __restrict__ QKV,
    const u16* __restrict__ Wbf, const float* __restrict__ bo,
    const float* __restrict__ gg, float* __restrict__ Y)
{
  __shared__ __align__(16) u16 As[256][72];   // 36,864 B
  __shared__ __align__(16) u16 Bs[64][72];    //  9,216 B
  __shared__ float red[4][64];
  __shared__ float sbias[256], sgain[256];
  const int nt = blockIdx.x, b = blockIdx.y;
  const int n0 = nt * 64;
  const int tid = threadIdx.x;
  const int lane = tid & 63, wv = tid >> 6;
  const int g = lane >> 4, c = lane & 15;
  const u16* ob = QKV + (size_t)b * QROWS * NPIX;   // aliased out (bf16)

  sbias[tid] = bo[tid];
  sgain[tid] = gg[tid];

  f32x4 acc[4][4];
  #pragma unroll
  for (int i = 0; i < 4; ++i)
    #pragma unroll
    for (int j = 0; j < 4; ++j) acc[i][j] = (f32x4){0.f, 0.f, 0.f, 0.f};

  for (int s = 0; s < 8; ++s) {
    const int k0 = s * 64;
    #pragma unroll
    for (int i = 0; i < 8; ++i) {
      const int flat = i * 256 + tid;
      const int row = flat >> 3, kc = flat & 7;
      *(uint4*)&As[row][kc * 8] =
          *(const uint4*)&Wbf[(size_t)row * HID + k0 + kc * 8];
    }
    {
      const int kb0 = wv * 16;
      u16 vals[16];
      #pragma unroll
      for (int kk = 0; kk < 16; ++kk)
        vals[kk] = ob[(size_t)(k0 + kb0 + kk) * NPIX + n0 + lane];
      u32 pk[8];
      #pragma unroll
      for (int j = 0; j < 8; ++j)
        pk[j] = (u32)vals[2*j] | ((u32)vals[2*j+1] << 16);
      *(uint4*)&Bs[lane][kb0]     = make_uint4(pk[0], pk[1], pk[2], pk[3]);
      *(uint4*)&Bs[lane][kb0 + 8] = make_uint4(pk[4], pk[5], pk[6], pk[7]);
    }
    __syncthreads();

    #pragma unroll
    for (int ks = 0; ks < 2; ++ks) {
      bf16x8 af[4], bfr[4];
      #pragma unroll
      for (int mf = 0; mf < 4; ++mf)
        af[mf] = *(const bf16x8*)&As[wv * 64 + mf * 16 + c][ks * 32 + g * 8];
      #pragma unroll
      for (int nf = 0; nf < 4; ++nf)
        bfr[nf] = *(const bf16x8*)&Bs[nf * 16 + c][ks * 32 + g * 8];
      #pragma unroll
      for (int mf = 0; mf < 4; ++mf)
        #pragma unroll
        for (int nf = 0; nf < 4; ++nf)
          acc[mf][nf] = __builtin_amdgcn_mfma_f32_16x16x32_bf16(
              af[mf], bfr[nf], acc[mf][nf], 0, 0, 0);
    }
    __syncthreads();
  }

  #pragma unroll
  for (int mf = 0; mf < 4; ++mf)
    #pragma unroll
    for (int r = 0; r < 4; ++r) {
      const float bb = sbias[wv * 64 + mf * 16 + g * 4 + r];
      #pragma unroll
      for (int nf = 0; nf < 4; ++nf) acc[mf][nf][r] += bb;
    }

  #pragma unroll
  for (int nf = 0; nf < 4; ++nf) {
    float v = 0.f;
    #pragma unroll
    for (int mf = 0; mf < 4; ++mf)
      #pragma unroll
      for (int r = 0; r < 4; ++r)
        v = fmaf(acc[mf][nf][r], acc[mf][nf][r], v);
    v += __shfl_xor(v, 16, 64);   // reduce over g
    v += __shfl_xor(v, 32, 64);
    if (g == 0) red[wv][nf * 16 + c] = v;
  }
  __syncthreads();
  float scale[4];
  #pragma unroll
  for (int nf = 0; nf < 4; ++nf) {
    const int col = nf * 16 + c;
    const float tot = red[0][col] + red[1][col] + red[2][col] + red[3][col];
    scale[nf] = 8.0f / fmaxf(sqrtf(tot), 1e-12f);
  }

  float* yb = Y + (size_t)b * CIN * NPIX;
  #pragma unroll
  for (int mf = 0; mf < 4; ++mf)
    #pragma unroll
    for (int r = 0; r < 4; ++r) {
      const int row = wv * 64 + mf * 16 + g * 4 + r;
      const float gr = sgain[row];
      #pragma unroll
      for (int nf = 0; nf < 4; ++nf)
        yb[(size_t)row * NPIX + n0 + nf * 16 + c] = acc[mf][nf][r] * scale[nf] * gr;
    }
}

extern "C" void kernel_launch(void* const* d_in, const int* in_sizes, int n_in,
                              void* d_out, int out_size, void* d_ws, size_t ws_size,
                              hipStream_t stream) {
  const float* x     = (const float*)d_in[0];
  const float* w_qkv = (const float*)d_in[1];
  const float* w_out = (const float*)d_in[2];
  const float* b_out = (const float*)d_in[3];
  const float* g     = (const float*)d_in[4];
  float* y = (float*)d_out;

  char* ws = (char*)d_ws;
  // layout (bytes):
  //   qkv  bf16 : 16*1536*4096*2 = 201,326,592   (q-section reused as `out`)
  //   xt   bf16 : 16*4096*256*2  =  33,554,432   at 201,326,592
  //     (xt is DEAD after k_qkv; ctx/ctxp/Sp alias into its window,
  //      all written strictly after k_qkv in stream order)
  //   ctx   f32 : alias 201,392,128 (2,097,152)
  //   ctxp  f32 : alias 203,489,280 (8,388,608)
  //   Sp    f32 : alias 211,877,888 (131,072)
  //   wbf  bf16 : 234,881,024 (262,144)
  //   wqb  bf16 : 235,143,168 (786,432)
  //   total     = 235,929,600
  u16*    qkv   = (u16*)(ws);
  u16*    xt    = (u16*)(ws + 201326592);
  float*  ctx   = (float*)(ws + 201392128);
  float*  ctxp  = (float*)(ws + 203489280);
  float*  Sp    = (float*)(ws + 211877888);
  u16*    wbf   = (u16*)(ws + 234881024);
  u16*    wqb   = (u16*)(ws + 235143168);

  if (ws_size < 235929600) {
    // diagnostic marker: if this shows up as absmax ~1e6, ws_size too small
    k_marker<<<dim3((out_size + 255) / 256), 256, 0, stream>>>(y, out_size);
    return;
  }

  k_cvt   <<<dim3(64),         256, 0, stream>>>(w_out, wbf);
  k_cvt   <<<dim3(192),        256, 0, stream>>>(w_qkv, wqb);
  k_xt    <<<dim3(64, 4, 16),  256, 0, stream>>>(x, xt);
  k_qkv   <<<dim3(6144),       256, 0, stream>>>(wqb, xt, qkv);
  k_ctx   <<<dim3(4, 8, 16),   256, 0, stream>>>(qkv, ctxp, Sp);
  k_ctxred<<<dim3(512),        256, 0, stream>>>(ctxp, Sp, ctx);
  k_qctx  <<<dim3(16, 8, 16),  256, 0, stream>>>(qkv, ctx);
  k_proj  <<<dim3(64, 16),     256, 0, stream>>>(qkv, wbf, b_out, g, y);
}

// Round 19
// 192.942 us; speedup vs baseline: 1.0313x; 1.0302x over previous
//
#include <hip/hip_runtime.h>
#include <hip/hip_bf16.h>

#define NPIX 4096
#define CIN  256
#define HID  512
#define QROWS 1536
#define NB   16

typedef unsigned int u32;
typedef unsigned short u16;
typedef float f32x4 __attribute__((ext_vector_type(4)));
typedef short bf16x8 __attribute__((ext_vector_type(8)));

__device__ __forceinline__ float bf2f(u16 u){
  union { u32 i; float f; } v; v.i = ((u32)u) << 16; return v.f;
}
__device__ __forceinline__ u16 f2bf(float f){
  union { float f; u32 u; } v; v.f = f;
  u32 r = v.u + 0x7fffu + ((v.u >> 16) & 1u);
  return (u16)(r >> 16);
}
__device__ __forceinline__ u32 pkbf(float a, float b){
  __hip_bfloat162 h = __float22bfloat162_rn(make_float2(a, b));
  union { __hip_bfloat162 h; u32 u; } cv; cv.h = h; return cv.u;
}
// async global(16B/lane) -> LDS (wave-uniform base + lane*16)
__device__ __forceinline__ void gload16(const u16* g, u16* l){
  __builtin_amdgcn_global_load_lds(
      (const __attribute__((address_space(1))) void*)g,
      (__attribute__((address_space(3))) void*)l, 16, 0, 0);
}

// Diagnostic: marker if workspace too small
__global__ void k_marker(float* y, int n){
  int i = blockIdx.x * 256 + threadIdx.x;
  if (i < n) y[i] = 1.0e6f;
}

// generic fp32 -> bf16 (8 elems/thread)
__global__ __launch_bounds__(256) void k_cvt(const float* __restrict__ src,
                                             u16* __restrict__ dst){
  const int i = (blockIdx.x * 256 + threadIdx.x) * 8;
  const float4 a = *(const float4*)(src + i);
  const float4 b = *(const float4*)(src + i + 4);
  *(uint4*)(dst + i) = make_uint4(pkbf(a.x,a.y), pkbf(a.z,a.w),
                                  pkbf(b.x,b.y), pkbf(b.z,b.w));
}

// ---------------------------------------------------------------------------
// K0: Xt[b][n][c] = bf16(X[b][c][n]) — transpose+convert pre-pass.
// ---------------------------------------------------------------------------
__global__ __launch_bounds__(256) void k_xt(const float* __restrict__ X,
                                            u16* __restrict__ Xt){
  __shared__ float ls[64][67];
  const int n0 = blockIdx.x * 64, c0 = blockIdx.y * 64, b = blockIdx.z;
  const int tid = threadIdx.x;
  const float* Xb = X + (size_t)b * CIN * NPIX;

  {
    const int r = tid >> 2, cq = (tid & 3) * 16;
    #pragma unroll
    for (int j = 0; j < 4; ++j)
      *(float4*)&ls[r][cq + j*4] = *(const float4*)&Xb[(size_t)(c0 + r) * NPIX + n0 + cq + j*4];
  }
  __syncthreads();
  {
    const int nr = tid >> 2, cs = (tid & 3) * 16;
    u32 pk[8];
    #pragma unroll
    for (int j = 0; j < 8; ++j)
      pk[j] = pkbf(ls[cs + 2*j][nr], ls[cs + 2*j + 1][nr]);
    u16* dst = Xt + (size_t)b * NPIX * CIN + (size_t)(n0 + nr) * CIN + c0 + cs;
    *(uint4*)(dst)     = make_uint4(pk[0], pk[1], pk[2], pk[3]);
    *(uint4*)(dst + 8) = make_uint4(pk[4], pk[5], pk[6], pk[7]);
  }
}

// ---------------------------------------------------------------------------
// K1 (MFMA, m97 structure): C[n][o] = Xt(n x c) . Wq(o x c); store qkv[o][n].
// 128n x 128o tile, K=256 in 4 BK=64 stages, global_load_lds width=16.
// ROUND-16 STRUCTURE (best measured: 81us) + launch_bounds(256,4):
// LDS 34.8KB allows 4 blocks/CU; 64 VGPR + 64 AGPR = 128 unified = exactly
// the 4-waves/SIMD budget. One-variable occupancy experiment (38% -> ~50%).
// ---------------------------------------------------------------------------
__global__ __launch_bounds__(256, 4) void k_qkv(
    const u16* __restrict__ Wq, const u16* __restrict__ Xt, u16* __restrict__ QKV)
{
  __shared__ __align__(16) u16 pool[17408];     // 34,816 B
  u16* As = pool;                 // 128*64 = 8192 u16 (Xt rows: n)
  u16* Bs = pool + 8192;          // 128*64 = 8192 u16 (Wq rows: o)

  const int flat = blockIdx.x;                  // 0..6143 (= 8*768)
  const int virt = (flat & 7) * 768 + (flat >> 3);
  const int o0 = (virt % 12) * 128;
  const int n0 = ((virt / 12) & 31) * 128;
  const int b  = virt / 384;

  const int tid = threadIdx.x;
  const int lane = tid & 63;
  const int wv = tid >> 6;             // 4 waves
  const int wr = wv >> 1, wc = wv & 1; // wave tile: n-rows wr*64, o-cols wc*64
  const int g  = lane >> 4;            // k-octet group
  const int c  = lane & 15;            // row/col within fragment
  const u16* Xb = Xt + (size_t)b * NPIX * CIN;

  const int grow = lane >> 3;          // 0..7
  const int gch  = (lane & 7) * 8;     // k offset

  f32x4 acc[4][4];
  #pragma unroll
  for (int i = 0; i < 4; ++i)
    #pragma unroll
    for (int j = 0; j < 4; ++j) acc[i][j] = (f32x4){0.f, 0.f, 0.f, 0.f};

  for (int s = 0; s < 4; ++s) {
    const int k0 = s * 64;
    #pragma unroll
    for (int i = 0; i < 4; ++i) {
      const int j = wv * 4 + i;                  // chunk 0..15
      const int row = j * 8 + grow;
      gload16(&Xb[(size_t)(n0 + row) * CIN + k0 + gch], &As[j * 512]);
      gload16(&Wq[(size_t)(o0 + row) * CIN + k0 + gch], &Bs[j * 512]);
    }
    __syncthreads();   // compiler drains vmcnt before barrier

    #pragma unroll
    for (int ks = 0; ks < 2; ++ks) {
      bf16x8 af[4], bfr[4];
      #pragma unroll
      for (int mf = 0; mf < 4; ++mf)
        af[mf] = *(const bf16x8*)&As[(wr * 64 + mf * 16 + c) * 64 + ks * 32 + g * 8];
      #pragma unroll
      for (int nf = 0; nf < 4; ++nf)
        bfr[nf] = *(const bf16x8*)&Bs[(wc * 64 + nf * 16 + c) * 64 + ks * 32 + g * 8];
      #pragma unroll
      for (int mf = 0; mf < 4; ++mf)
        #pragma unroll
        for (int nf = 0; nf < 4; ++nf)
          acc[mf][nf] = __builtin_amdgcn_mfma_f32_16x16x32_bf16(
              af[mf], bfr[nf], acc[mf][nf], 0, 0, 0);
    }
    __syncthreads();
  }

  // ---- epilogue: scatter into pool[o(128)][n(128)+pad8], coalesced store --
  #pragma unroll
  for (int mf = 0; mf < 4; ++mf) {
    const int nrow = wr * 64 + mf * 16 + g * 4;
    #pragma unroll
    for (int nf = 0; nf < 4; ++nf) {
      const int ocol = wc * 64 + nf * 16 + c;
      #pragma unroll
      for (int r = 0; r < 4; ++r)
        pool[ocol * 136 + nrow + r] = f2bf(acc[mf][nf][r]);
    }
  }
  __syncthreads();
  u16* dst = QKV + (size_t)b * QROWS * NPIX;
  #pragma unroll
  for (int i = 0; i < 8; ++i) {
    const int f2 = i * 256 + tid;
    const int orow = f2 >> 4, ch = f2 & 15;   // 128 rows x 16 16B-chunks
    const uint4 v = *(const uint4*)&pool[orow * 136 + ch * 8];
    *(uint4*)&dst[(size_t)(o0 + orow) * NPIX + n0 + ch * 8] = v;
  }
}

// ---------------------------------------------------------------------------
// K3 (MFMA, no-max softmax): ctxp[split][b,h,d,e] = sum_{n in split}
// exp(k[d,n]) * v[e,n]  (UNNORMALIZED), plus Sp[split][b,h,d] = sum exp.
// ---------------------------------------------------------------------------
__global__ __launch_bounds__(256) void k_ctx(const u16* __restrict__ QKV,
    float* __restrict__ ctxp, float* __restrict__ Sp)
{
  __shared__ __align__(16) u16 ks[64 * 72];   // 9,216 B
  __shared__ __align__(16) u16 vs[64 * 72];   // 9,216 B
  const int split = blockIdx.x, h = blockIdx.y, b = blockIdx.z;
  const int tid = threadIdx.x;
  const int lane = tid & 63, wv = tid >> 6;
  const int g = lane >> 4, c = lane & 15;
  const u16* kb = QKV + ((size_t)b * QROWS + HID     + h * 64) * NPIX;
  const u16* vb = QKV + ((size_t)b * QROWS + 2 * HID + h * 64) * NPIX;

  const int srow = tid >> 2;          // staging row 0..63 (4 thr/row)
  const int sch  = (tid & 3) * 16;    // staging n-chunk

  f32x4 acc[4];
  #pragma unroll
  for (int j = 0; j < 4; ++j) acc[j] = (f32x4){0.f, 0.f, 0.f, 0.f};
  float s_part = 0.f;

  for (int t = 0; t < 16; ++t) {
    const int n0 = split * 1024 + t * 64;
    {
      const uint4 r0 = *(const uint4*)(kb + (size_t)srow * NPIX + n0 + sch);
      const uint4 r1 = *(const uint4*)(kb + (size_t)srow * NPIX + n0 + sch + 8);
      const u32 w[8] = {r0.x, r0.y, r0.z, r0.w, r1.x, r1.y, r1.z, r1.w};
      u32 pk[8];
      #pragma unroll
      for (int j = 0; j < 8; ++j) {
        const float lo = __expf(bf2f((u16)(w[j] & 0xffff)));
        const float hi = __expf(bf2f((u16)(w[j] >> 16)));
        s_part += lo + hi;
        pk[j] = pkbf(lo, hi);
      }
      *(uint4*)&ks[srow * 72 + sch]     = make_uint4(pk[0], pk[1], pk[2], pk[3]);
      *(uint4*)&ks[srow * 72 + sch + 8] = make_uint4(pk[4], pk[5], pk[6], pk[7]);
      const uint4 v0 = *(const uint4*)(vb + (size_t)srow * NPIX + n0 + sch);
      const uint4 v1 = *(const uint4*)(vb + (size_t)srow * NPIX + n0 + sch + 8);
      *(uint4*)&vs[srow * 72 + sch]     = v0;
      *(uint4*)&vs[srow * 72 + sch + 8] = v1;
    }
    __syncthreads();
    #pragma unroll
    for (int ks2 = 0; ks2 < 2; ++ks2) {
      const bf16x8 af = *(const bf16x8*)&ks[(wv * 16 + c) * 72 + ks2 * 32 + g * 8];
      #pragma unroll
      for (int nf = 0; nf < 4; ++nf) {
        const bf16x8 bf = *(const bf16x8*)&vs[(nf * 16 + c) * 72 + ks2 * 32 + g * 8];
        acc[nf] = __builtin_amdgcn_mfma_f32_16x16x32_bf16(af, bf, acc[nf], 0, 0, 0);
      }
    }
    __syncthreads();
  }
  s_part += __shfl_xor(s_part, 1, 64);
  s_part += __shfl_xor(s_part, 2, 64);
  if ((tid & 3) == 0)
    Sp[(size_t)split * 8192 + (b * 8 + h) * 64 + srow] = s_part;

  float* dst = ctxp + (size_t)split * (NB*8*64*64) + ((size_t)(b*8+h)) * 4096;
  #pragma unroll
  for (int nf = 0; nf < 4; ++nf)
    #pragma unroll
    for (int r = 0; r < 4; ++r)
      dst[(wv*16 + g*4 + r) * 64 + nf*16 + c] = acc[nf][r];
}

// K3b: reduce 4 partials + normalize by S (deferred softmax denominator)
__global__ __launch_bounds__(256) void k_ctxred(const float* __restrict__ ctxp,
                                                const float* __restrict__ Sp,
                                                float* __restrict__ ctx)
{
  const int SZ = NB*8*64*64;  // 524288
  const int i = (blockIdx.x * 256 + threadIdx.x) * 4;
  const int bh = i >> 12, d = (i >> 6) & 63;
  const int si = bh * 64 + d;
  const float S = Sp[si] + Sp[8192 + si] + Sp[16384 + si] + Sp[24576 + si];
  const float inv = 1.0f / S;
  float4 a  = *(const float4*)(ctxp + i);
  const float4 c1 = *(const float4*)(ctxp + SZ   + i);
  const float4 c2 = *(const float4*)(ctxp + 2*SZ + i);
  const float4 c3 = *(const float4*)(ctxp + 3*SZ + i);
  a.x = (a.x + c1.x + c2.x + c3.x) * inv;
  a.y = (a.y + c1.y + c2.y + c3.y) * inv;
  a.z = (a.z + c1.z + c2.z + c3.z) * inv;
  a.w = (a.w + c1.w + c2.w + c3.w) * inv;
  *(float4*)(ctx + i) = a;
}

// ---------------------------------------------------------------------------
// K4 (MFMA): out[e,n] = sum_d ctx[d,e]*q'[d,n], q' = softmax_d(q)*0.125.
// C[n][e] = q'(n x d) . ctxT(e x d). Thread-local softmax (d=64 in regs).
// ---------------------------------------------------------------------------
__global__ __launch_bounds__(256) void k_qctx(u16* __restrict__ QKV,
    const float* __restrict__ ctx)
{
  __shared__ __align__(16) u16 As[256 * 72];   // 36,864 B  (q'[n][d])
  __shared__ __align__(16) u16 Bs[64 * 72];    //  9,216 B  (ctxT[e][d])
  const int nt = blockIdx.x, h = blockIdx.y, b = blockIdx.z;
  const int n0 = nt * 256;
  const int tid = threadIdx.x;
  const int lane = tid & 63, wv = tid >> 6;
  const int g = lane >> 4, c = lane & 15;

  const float* cbase = ctx + ((size_t)(b*8+h)) * 4096;
  #pragma unroll
  for (int j = 0; j < 16; ++j) {
    const int idx = tid + j * 256;      // coalesced f32 read
    const int d = idx >> 6, e = idx & 63;
    Bs[e * 72 + d] = f2bf(cbase[idx]);
  }

  const u16* qb = QKV + ((size_t)b*QROWS + h*64) * NPIX;
  float vals[64];
  float mx = -3.0e38f;
  #pragma unroll
  for (int d = 0; d < 64; ++d) {
    vals[d] = bf2f(qb[(size_t)d * NPIX + n0 + tid]);
    mx = fmaxf(mx, vals[d]);
  }
  float s = 0.f;
  #pragma unroll
  for (int d = 0; d < 64; ++d) { vals[d] = __expf(vals[d] - mx); s += vals[d]; }
  const float sc = 0.125f / s;
  #pragma unroll
  for (int q = 0; q < 8; ++q) {
    u32 pk[4];
    #pragma unroll
    for (int p = 0; p < 4; ++p)
      pk[p] = pkbf(vals[q*8 + 2*p] * sc, vals[q*8 + 2*p + 1] * sc);
    *(uint4*)&As[tid * 72 + q * 8] = make_uint4(pk[0], pk[1], pk[2], pk[3]);
  }
  __syncthreads();

  f32x4 acc[4][4];
  #pragma unroll
  for (int i = 0; i < 4; ++i)
    #pragma unroll
    for (int j = 0; j < 4; ++j) acc[i][j] = (f32x4){0.f, 0.f, 0.f, 0.f};
  #pragma unroll
  for (int ks = 0; ks < 2; ++ks) {
    bf16x8 af[4], bfr[4];
    #pragma unroll
    for (int mf = 0; mf < 4; ++mf)
      af[mf] = *(const bf16x8*)&As[(wv * 64 + mf * 16 + c) * 72 + ks * 32 + g * 8];
    #pragma unroll
    for (int nf = 0; nf < 4; ++nf)
      bfr[nf] = *(const bf16x8*)&Bs[(nf * 16 + c) * 72 + ks * 32 + g * 8];
    #pragma unroll
    for (int mf = 0; mf < 4; ++mf)
      #pragma unroll
      for (int nf = 0; nf < 4; ++nf)
        acc[mf][nf] = __builtin_amdgcn_mfma_f32_16x16x32_bf16(
            af[mf], bfr[nf], acc[mf][nf], 0, 0, 0);
  }
  __syncthreads();

  u16* pool = As;   // 64*264 = 16,896 u16 <= 18,432 u16 of As
  #pragma unroll
  for (int mf = 0; mf < 4; ++mf) {
    const int nrow = wv * 64 + mf * 16 + g * 4;
    #pragma unroll
    for (int nf = 0; nf < 4; ++nf) {
      const int ecol = nf * 16 + c;
      #pragma unroll
      for (int r = 0; r < 4; ++r)
        pool[ecol * 264 + nrow + r] = f2bf(acc[mf][nf][r]);
    }
  }
  __syncthreads();
  u16* ob = QKV + ((size_t)b*QROWS + h*64) * NPIX;   // aliased out
  #pragma unroll
  for (int i = 0; i < 8; ++i) {
    const int f2 = i * 256 + tid;
    const int erow = f2 >> 5, ch = f2 & 31;   // 64 rows x 32 16B-chunks
    const uint4 v = *(const uint4*)&pool[erow * 264 + ch * 8];
    *(uint4*)&ob[(size_t)erow * NPIX + n0 + ch * 8] = v;
  }
}

// ---------------------------------------------------------------------------
// K5 (MFMA): y[c,n] = sum_e Wo[c,e]*out[e,n] + bo[c]; L2-norm over c; *g*8
// ---------------------------------------------------------------------------
__global__ __launch_bounds__(256) void k_proj(const u16* __restrict__ QKV,
    const u16* __restrict__ Wbf, const float* __restrict__ bo,
    const float* __restrict__ gg, float* __restrict__ Y)
{
  __shared__ __align__(16) u16 As[256][72];   // 36,864 B
  __shared__ __align__(16) u16 Bs[64][72];    //  9,216 B
  __shared__ float red[4][64];
  __shared__ float sbias[256], sgain[256];
  const int nt = blockIdx.x, b = blockIdx.y;
  const int n0 = nt * 64;
  const int tid = threadIdx.x;
  const int lane = tid & 63, wv = tid >> 6;
  const int g = lane >> 4, c = lane & 15;
  const u16* ob = QKV + (size_t)b * QROWS * NPIX;   // aliased out (bf16)

  sbias[tid] = bo[tid];
  sgain[tid] = gg[tid];

  f32x4 acc[4][4];
  #pragma unroll
  for (int i = 0; i < 4; ++i)
    #pragma unroll
    for (int j = 0; j < 4; ++j) acc[i][j] = (f32x4){0.f, 0.f, 0.f, 0.f};

  for (int s = 0; s < 8; ++s) {
    const int k0 = s * 64;
    #pragma unroll
    for (int i = 0; i < 8; ++i) {
      const int flat = i * 256 + tid;
      const int row = flat >> 3, kc = flat & 7;
      *(uint4*)&As[row][kc * 8] =
          *(const uint4*)&Wbf[(size_t)row * HID + k0 + kc * 8];
    }
    {
      const int kb0 = wv * 16;
      u16 vals[16];
      #pragma unroll
      for (int kk = 0; kk < 16; ++kk)
        vals[kk] = ob[(size_t)(k0 + kb0 + kk) * NPIX + n0 + lane];
      u32 pk[8];
      #pragma unroll
      for (int j = 0; j < 8; ++j)
        pk[j] = (u32)vals[2*j] | ((u32)vals[2*j+1] << 16);
      *(uint4*)&Bs[lane][kb0]     = make_uint4(pk[0], pk[1], pk[2], pk[3]);
      *(uint4*)&Bs[lane][kb0 + 8] = make_uint4(pk[4], pk[5], pk[6], pk[7]);
    }
    __syncthreads();

    #pragma unroll
    for (int ks = 0; ks < 2; ++ks) {
      bf16x8 af[4], bfr[4];
      #pragma unroll
      for (int mf = 0; mf < 4; ++mf)
        af[mf] = *(const bf16x8*)&As[wv * 64 + mf * 16 + c][ks * 32 + g * 8];
      #pragma unroll
      for (int nf = 0; nf < 4; ++nf)
        bfr[nf] = *(const bf16x8*)&Bs[nf * 16 + c][ks * 32 + g * 8];
      #pragma unroll
      for (int mf = 0; mf < 4; ++mf)
        #pragma unroll
        for (int nf = 0; nf < 4; ++nf)
          acc[mf][nf] = __builtin_amdgcn_mfma_f32_16x16x32_bf16(
              af[mf], bfr[nf], acc[mf][nf], 0, 0, 0);
    }
    __syncthreads();
  }

  #pragma unroll
  for (int mf = 0; mf < 4; ++mf)
    #pragma unroll
    for (int r = 0; r < 4; ++r) {
      const float bb = sbias[wv * 64 + mf * 16 + g * 4 + r];
      #pragma unroll
      for (int nf = 0; nf < 4; ++nf) acc[mf][nf][r] += bb;
    }

  #pragma unroll
  for (int nf = 0; nf < 4; ++nf) {
    float v = 0.f;
    #pragma unroll
    for (int mf = 0; mf < 4; ++mf)
      #pragma unroll
      for (int r = 0; r < 4; ++r)
        v = fmaf(acc[mf][nf][r], acc[mf][nf][r], v);
    v += __shfl_xor(v, 16, 64);   // reduce over g
    v += __shfl_xor(v, 32, 64);
    if (g == 0) red[wv][nf * 16 + c] = v;
  }
  __syncthreads();
  float scale[4];
  #pragma unroll
  for (int nf = 0; nf < 4; ++nf) {
    const int col = nf * 16 + c;
    const float tot = red[0][col] + red[1][col] + red[2][col] + red[3][col];
    scale[nf] = 8.0f / fmaxf(sqrtf(tot), 1e-12f);
  }

  float* yb = Y + (size_t)b * CIN * NPIX;
  #pragma unroll
  for (int mf = 0; mf < 4; ++mf)
    #pragma unroll
    for (int r = 0; r < 4; ++r) {
      const int row = wv * 64 + mf * 16 + g * 4 + r;
      const float gr = sgain[row];
      #pragma unroll
      for (int nf = 0; nf < 4; ++nf)
        yb[(size_t)row * NPIX + n0 + nf * 16 + c] = acc[mf][nf][r] * scale[nf] * gr;
    }
}

extern "C" void kernel_launch(void* const* d_in, const int* in_sizes, int n_in,
                              void* d_out, int out_size, void* d_ws, size_t ws_size,
                              hipStream_t stream) {
  const float* x     = (const float*)d_in[0];
  const float* w_qkv = (const float*)d_in[1];
  const float* w_out = (const float*)d_in[2];
  const float* b_out = (const float*)d_in[3];
  const float* g     = (const float*)d_in[4];
  float* y = (float*)d_out;

  char* ws = (char*)d_ws;
  // layout (bytes):
  //   qkv  bf16 : 16*1536*4096*2 = 201,326,592   (q-section reused as `out`)
  //   xt   bf16 : 16*4096*256*2  =  33,554,432   at 201,326,592
  //     (xt is DEAD after k_qkv; ctx/ctxp/Sp alias into its window,
  //      all written strictly after k_qkv in stream order)
  //   ctx   f32 : alias 201,392,128 (2,097,152)
  //   ctxp  f32 : alias 203,489,280 (8,388,608)
  //   Sp    f32 : alias 211,877,888 (131,072)
  //   wbf  bf16 : 234,881,024 (262,144)
  //   wqb  bf16 : 235,143,168 (786,432)
  //   total     = 235,929,600
  u16*    qkv   = (u16*)(ws);
  u16*    xt    = (u16*)(ws + 201326592);
  float*  ctx   = (float*)(ws + 201392128);
  float*  ctxp  = (float*)(ws + 203489280);
  float*  Sp    = (float*)(ws + 211877888);
  u16*    wbf   = (u16*)(ws + 234881024);
  u16*    wqb   = (u16*)(ws + 235143168);

  if (ws_size < 235929600) {
    // diagnostic marker: if this shows up as absmax ~1e6, ws_size too small
    k_marker<<<dim3((out_size + 255) / 256), 256, 0, stream>>>(y, out_size);
    return;
  }

  k_cvt   <<<dim3(64),         256, 0, stream>>>(w_out, wbf);
  k_cvt   <<<dim3(192),        256, 0, stream>>>(w_qkv, wqb);
  k_xt    <<<dim3(64, 4, 16),  256, 0, stream>>>(x, xt);
  k_qkv   <<<dim3(6144),       256, 0, stream>>>(wqb, xt, qkv);
  k_ctx   <<<dim3(4, 8, 16),   256, 0, stream>>>(qkv, ctxp, Sp);
  k_ctxred<<<dim3(512),        256, 0, stream>>>(ctxp, Sp, ctx);
  k_qctx  <<<dim3(16, 8, 16),  256, 0, stream>>>(qkv, ctx);
  k_proj  <<<dim3(64, 16),     256, 0, stream>>>(qkv, wbf, b_out, g, y);
}

// Round 20
// 191.990 us; speedup vs baseline: 1.0364x; 1.0050x over previous
//
#include <hip/hip_runtime.h>
#include <hip/hip_bf16.h>

#define NPIX 4096
#define CIN  256
#define HID  512
#define QROWS 1536
#define NB   16

typedef unsigned int u32;
typedef unsigned short u16;
typedef float f32x4 __attribute__((ext_vector_type(4)));
typedef short bf16x8 __attribute__((ext_vector_type(8)));

__device__ __forceinline__ float bf2f(u16 u){
  union { u32 i; float f; } v; v.i = ((u32)u) << 16; return v.f;
}
__device__ __forceinline__ u16 f2bf(float f){
  union { float f; u32 u; } v; v.f = f;
  u32 r = v.u + 0x7fffu + ((v.u >> 16) & 1u);
  return (u16)(r >> 16);
}
__device__ __forceinline__ u32 pkbf(float a, float b){
  __hip_bfloat162 h = __float22bfloat162_rn(make_float2(a, b));
  union { __hip_bfloat162 h; u32 u; } cv; cv.h = h; return cv.u;
}
// async global(16B/lane) -> LDS (wave-uniform base + lane*16)
__device__ __forceinline__ void gload16(const u16* g, u16* l){
  __builtin_amdgcn_global_load_lds(
      (const __attribute__((address_space(1))) void*)g,
      (__attribute__((address_space(3))) void*)l, 16, 0, 0);
}

// Diagnostic: marker if workspace too small
__global__ void k_marker(float* y, int n){
  int i = blockIdx.x * 256 + threadIdx.x;
  if (i < n) y[i] = 1.0e6f;
}

// generic fp32 -> bf16 (8 elems/thread)
__global__ __launch_bounds__(256) void k_cvt(const float* __restrict__ src,
                                             u16* __restrict__ dst){
  const int i = (blockIdx.x * 256 + threadIdx.x) * 8;
  const float4 a = *(const float4*)(src + i);
  const float4 b = *(const float4*)(src + i + 4);
  *(uint4*)(dst + i) = make_uint4(pkbf(a.x,a.y), pkbf(a.z,a.w),
                                  pkbf(b.x,b.y), pkbf(b.z,b.w));
}

// ---------------------------------------------------------------------------
// K0: Xt[b][n][c] = bf16(X[b][c][n]) — transpose+convert pre-pass.
// ---------------------------------------------------------------------------
__global__ __launch_bounds__(256) void k_xt(const float* __restrict__ X,
                                            u16* __restrict__ Xt){
  __shared__ float ls[64][67];
  const int n0 = blockIdx.x * 64, c0 = blockIdx.y * 64, b = blockIdx.z;
  const int tid = threadIdx.x;
  const float* Xb = X + (size_t)b * CIN * NPIX;

  {
    const int r = tid >> 2, cq = (tid & 3) * 16;
    #pragma unroll
    for (int j = 0; j < 4; ++j)
      *(float4*)&ls[r][cq + j*4] = *(const float4*)&Xb[(size_t)(c0 + r) * NPIX + n0 + cq + j*4];
  }
  __syncthreads();
  {
    const int nr = tid >> 2, cs = (tid & 3) * 16;
    u32 pk[8];
    #pragma unroll
    for (int j = 0; j < 8; ++j)
      pk[j] = pkbf(ls[cs + 2*j][nr], ls[cs + 2*j + 1][nr]);
    u16* dst = Xt + (size_t)b * NPIX * CIN + (size_t)(n0 + nr) * CIN + c0 + cs;
    *(uint4*)(dst)     = make_uint4(pk[0], pk[1], pk[2], pk[3]);
    *(uint4*)(dst + 8) = make_uint4(pk[4], pk[5], pk[6], pk[7]);
  }
}

// ---------------------------------------------------------------------------
// K1 (MFMA, m97 structure): C[n][o] = Xt(n x c) . Wq(o x c); store qkv[o][n].
// 128n x 128o tile, K=256 in 4 BK=64 stages, global_load_lds width=16.
// ROUND-16 STRUCTURE (best measured: 81us) + launch_bounds(256,4):
// LDS 34.8KB allows 4 blocks/CU; 64 VGPR + 64 AGPR = 128 unified = exactly
// the 4-waves/SIMD budget. One-variable occupancy experiment (38% -> ~50%).
// ---------------------------------------------------------------------------
__global__ __launch_bounds__(256, 4) void k_qkv(
    const u16* __restrict__ Wq, const u16* __restrict__ Xt, u16* __restrict__ QKV)
{
  __shared__ __align__(16) u16 pool[17408];     // 34,816 B
  u16* As = pool;                 // 128*64 = 8192 u16 (Xt rows: n)
  u16* Bs = pool + 8192;          // 128*64 = 8192 u16 (Wq rows: o)

  const int flat = blockIdx.x;                  // 0..6143 (= 8*768)
  const int virt = (flat & 7) * 768 + (flat >> 3);
  const int o0 = (virt % 12) * 128;
  const int n0 = ((virt / 12) & 31) * 128;
  const int b  = virt / 384;

  const int tid = threadIdx.x;
  const int lane = tid & 63;
  const int wv = tid >> 6;             // 4 waves
  const int wr = wv >> 1, wc = wv & 1; // wave tile: n-rows wr*64, o-cols wc*64
  const int g  = lane >> 4;            // k-octet group
  const int c  = lane & 15;            // row/col within fragment
  const u16* Xb = Xt + (size_t)b * NPIX * CIN;

  const int grow = lane >> 3;          // 0..7
  const int gch  = (lane & 7) * 8;     // k offset

  f32x4 acc[4][4];
  #pragma unroll
  for (int i = 0; i < 4; ++i)
    #pragma unroll
    for (int j = 0; j < 4; ++j) acc[i][j] = (f32x4){0.f, 0.f, 0.f, 0.f};

  for (int s = 0; s < 4; ++s) {
    const int k0 = s * 64;
    #pragma unroll
    for (int i = 0; i < 4; ++i) {
      const int j = wv * 4 + i;                  // chunk 0..15
      const int row = j * 8 + grow;
      gload16(&Xb[(size_t)(n0 + row) * CIN + k0 + gch], &As[j * 512]);
      gload16(&Wq[(size_t)(o0 + row) * CIN + k0 + gch], &Bs[j * 512]);
    }
    __syncthreads();   // compiler drains vmcnt before barrier

    #pragma unroll
    for (int ks = 0; ks < 2; ++ks) {
      bf16x8 af[4], bfr[4];
      #pragma unroll
      for (int mf = 0; mf < 4; ++mf)
        af[mf] = *(const bf16x8*)&As[(wr * 64 + mf * 16 + c) * 64 + ks * 32 + g * 8];
      #pragma unroll
      for (int nf = 0; nf < 4; ++nf)
        bfr[nf] = *(const bf16x8*)&Bs[(wc * 64 + nf * 16 + c) * 64 + ks * 32 + g * 8];
      #pragma unroll
      for (int mf = 0; mf < 4; ++mf)
        #pragma unroll
        for (int nf = 0; nf < 4; ++nf)
          acc[mf][nf] = __builtin_amdgcn_mfma_f32_16x16x32_bf16(
              af[mf], bfr[nf], acc[mf][nf], 0, 0, 0);
    }
    __syncthreads();
  }

  // ---- epilogue: scatter into pool[o(128)][n(128)+pad8], coalesced store --
  #pragma unroll
  for (int mf = 0; mf < 4; ++mf) {
    const int nrow = wr * 64 + mf * 16 + g * 4;
    #pragma unroll
    for (int nf = 0; nf < 4; ++nf) {
      const int ocol = wc * 64 + nf * 16 + c;
      #pragma unroll
      for (int r = 0; r < 4; ++r)
        pool[ocol * 136 + nrow + r] = f2bf(acc[mf][nf][r]);
    }
  }
  __syncthreads();
  u16* dst = QKV + (size_t)b * QROWS * NPIX;
  #pragma unroll
  for (int i = 0; i < 8; ++i) {
    const int f2 = i * 256 + tid;
    const int orow = f2 >> 4, ch = f2 & 15;   // 128 rows x 16 16B-chunks
    const uint4 v = *(const uint4*)&pool[orow * 136 + ch * 8];
    *(uint4*)&dst[(size_t)(o0 + orow) * NPIX + n0 + ch * 8] = v;
  }
}

// ---------------------------------------------------------------------------
// K3 (MFMA, no-max softmax): ctxp[split][b,h,d,e] = sum_{n in split}
// exp(k[d,n]) * v[e,n]  (UNNORMALIZED), plus Sp[split][b,h,d] = sum exp.
// ---------------------------------------------------------------------------
__global__ __launch_bounds__(256) void k_ctx(const u16* __restrict__ QKV,
    float* __restrict__ ctxp, float* __restrict__ Sp)
{
  __shared__ __align__(16) u16 ks[64 * 72];   // 9,216 B
  __shared__ __align__(16) u16 vs[64 * 72];   // 9,216 B
  const int split = blockIdx.x, h = blockIdx.y, b = blockIdx.z;
  const int tid = threadIdx.x;
  const int lane = tid & 63, wv = tid >> 6;
  const int g = lane >> 4, c = lane & 15;
  const u16* kb = QKV + ((size_t)b * QROWS + HID     + h * 64) * NPIX;
  const u16* vb = QKV + ((size_t)b * QROWS + 2 * HID + h * 64) * NPIX;

  const int srow = tid >> 2;          // staging row 0..63 (4 thr/row)
  const int sch  = (tid & 3) * 16;    // staging n-chunk

  f32x4 acc[4];
  #pragma unroll
  for (int j = 0; j < 4; ++j) acc[j] = (f32x4){0.f, 0.f, 0.f, 0.f};
  float s_part = 0.f;

  for (int t = 0; t < 16; ++t) {
    const int n0 = split * 1024 + t * 64;
    {
      const uint4 r0 = *(const uint4*)(kb + (size_t)srow * NPIX + n0 + sch);
      const uint4 r1 = *(const uint4*)(kb + (size_t)srow * NPIX + n0 + sch + 8);
      const u32 w[8] = {r0.x, r0.y, r0.z, r0.w, r1.x, r1.y, r1.z, r1.w};
      u32 pk[8];
      #pragma unroll
      for (int j = 0; j < 8; ++j) {
        const float lo = __expf(bf2f((u16)(w[j] & 0xffff)));
        const float hi = __expf(bf2f((u16)(w[j] >> 16)));
        s_part += lo + hi;
        pk[j] = pkbf(lo, hi);
      }
      *(uint4*)&ks[srow * 72 + sch]     = make_uint4(pk[0], pk[1], pk[2], pk[3]);
      *(uint4*)&ks[srow * 72 + sch + 8] = make_uint4(pk[4], pk[5], pk[6], pk[7]);
      const uint4 v0 = *(const uint4*)(vb + (size_t)srow * NPIX + n0 + sch);
      const uint4 v1 = *(const uint4*)(vb + (size_t)srow * NPIX + n0 + sch + 8);
      *(uint4*)&vs[srow * 72 + sch]     = v0;
      *(uint4*)&vs[srow * 72 + sch + 8] = v1;
    }
    __syncthreads();
    #pragma unroll
    for (int ks2 = 0; ks2 < 2; ++ks2) {
      const bf16x8 af = *(const bf16x8*)&ks[(wv * 16 + c) * 72 + ks2 * 32 + g * 8];
      #pragma unroll
      for (int nf = 0; nf < 4; ++nf) {
        const bf16x8 bf = *(const bf16x8*)&vs[(nf * 16 + c) * 72 + ks2 * 32 + g * 8];
        acc[nf] = __builtin_amdgcn_mfma_f32_16x16x32_bf16(af, bf, acc[nf], 0, 0, 0);
      }
    }
    __syncthreads();
  }
  s_part += __shfl_xor(s_part, 1, 64);
  s_part += __shfl_xor(s_part, 2, 64);
  if ((tid & 3) == 0)
    Sp[(size_t)split * 8192 + (b * 8 + h) * 64 + srow] = s_part;

  float* dst = ctxp + (size_t)split * (NB*8*64*64) + ((size_t)(b*8+h)) * 4096;
  #pragma unroll
  for (int nf = 0; nf < 4; ++nf)
    #pragma unroll
    for (int r = 0; r < 4; ++r)
      dst[(wv*16 + g*4 + r) * 64 + nf*16 + c] = acc[nf][r];
}

// K3b: reduce 4 partials + normalize by S (deferred softmax denominator)
__global__ __launch_bounds__(256) void k_ctxred(const float* __restrict__ ctxp,
                                                const float* __restrict__ Sp,
                                                float* __restrict__ ctx)
{
  const int SZ = NB*8*64*64;  // 524288
  const int i = (blockIdx.x * 256 + threadIdx.x) * 4;
  const int bh = i >> 12, d = (i >> 6) & 63;
  const int si = bh * 64 + d;
  const float S = Sp[si] + Sp[8192 + si] + Sp[16384 + si] + Sp[24576 + si];
  const float inv = 1.0f / S;
  float4 a  = *(const float4*)(ctxp + i);
  const float4 c1 = *(const float4*)(ctxp + SZ   + i);
  const float4 c2 = *(const float4*)(ctxp + 2*SZ + i);
  const float4 c3 = *(const float4*)(ctxp + 3*SZ + i);
  a.x = (a.x + c1.x + c2.x + c3.x) * inv;
  a.y = (a.y + c1.y + c2.y + c3.y) * inv;
  a.z = (a.z + c1.z + c2.z + c3.z) * inv;
  a.w = (a.w + c1.w + c2.w + c3.w) * inv;
  *(float4*)(ctx + i) = a;
}

// ---------------------------------------------------------------------------
// K4 (MFMA): out[e,n] = sum_d ctx[d,e]*q'[d,n], q' = softmax_d(q)*0.125.
// C[n][e] = q'(n x d) . ctxT(e x d). Thread-local softmax (d=64 in regs).
// ---------------------------------------------------------------------------
__global__ __launch_bounds__(256) void k_qctx(u16* __restrict__ QKV,
    const float* __restrict__ ctx)
{
  __shared__ __align__(16) u16 As[256 * 72];   // 36,864 B  (q'[n][d])
  __shared__ __align__(16) u16 Bs[64 * 72];    //  9,216 B  (ctxT[e][d])
  const int nt = blockIdx.x, h = blockIdx.y, b = blockIdx.z;
  const int n0 = nt * 256;
  const int tid = threadIdx.x;
  const int lane = tid & 63, wv = tid >> 6;
  const int g = lane >> 4, c = lane & 15;

  const float* cbase = ctx + ((size_t)(b*8+h)) * 4096;
  #pragma unroll
  for (int j = 0; j < 16; ++j) {
    const int idx = tid + j * 256;      // coalesced f32 read
    const int d = idx >> 6, e = idx & 63;
    Bs[e * 72 + d] = f2bf(cbase[idx]);
  }

  const u16* qb = QKV + ((size_t)b*QROWS + h*64) * NPIX;
  float vals[64];
  float mx = -3.0e38f;
  #pragma unroll
  for (int d = 0; d < 64; ++d) {
    vals[d] = bf2f(qb[(size_t)d * NPIX + n0 + tid]);
    mx = fmaxf(mx, vals[d]);
  }
  float s = 0.f;
  #pragma unroll
  for (int d = 0; d < 64; ++d) { vals[d] = __expf(vals[d] - mx); s += vals[d]; }
  const float sc = 0.125f / s;
  #pragma unroll
  for (int q = 0; q < 8; ++q) {
    u32 pk[4];
    #pragma unroll
    for (int p = 0; p < 4; ++p)
      pk[p] = pkbf(vals[q*8 + 2*p] * sc, vals[q*8 + 2*p + 1] * sc);
    *(uint4*)&As[tid * 72 + q * 8] = make_uint4(pk[0], pk[1], pk[2], pk[3]);
  }
  __syncthreads();

  f32x4 acc[4][4];
  #pragma unroll
  for (int i = 0; i < 4; ++i)
    #pragma unroll
    for (int j = 0; j < 4; ++j) acc[i][j] = (f32x4){0.f, 0.f, 0.f, 0.f};
  #pragma unroll
  for (int ks = 0; ks < 2; ++ks) {
    bf16x8 af[4], bfr[4];
    #pragma unroll
    for (int mf = 0; mf < 4; ++mf)
      af[mf] = *(const bf16x8*)&As[(wv * 64 + mf * 16 + c) * 72 + ks * 32 + g * 8];
    #pragma unroll
    for (int nf = 0; nf < 4; ++nf)
      bfr[nf] = *(const bf16x8*)&Bs[(nf * 16 + c) * 72 + ks * 32 + g * 8];
    #pragma unroll
    for (int mf = 0; mf < 4; ++mf)
      #pragma unroll
      for (int nf = 0; nf < 4; ++nf)
        acc[mf][nf] = __builtin_amdgcn_mfma_f32_16x16x32_bf16(
            af[mf], bfr[nf], acc[mf][nf], 0, 0, 0);
  }
  __syncthreads();

  u16* pool = As;   // 64*264 = 16,896 u16 <= 18,432 u16 of As
  #pragma unroll
  for (int mf = 0; mf < 4; ++mf) {
    const int nrow = wv * 64 + mf * 16 + g * 4;
    #pragma unroll
    for (int nf = 0; nf < 4; ++nf) {
      const int ecol = nf * 16 + c;
      #pragma unroll
      for (int r = 0; r < 4; ++r)
        pool[ecol * 264 + nrow + r] = f2bf(acc[mf][nf][r]);
    }
  }
  __syncthreads();
  u16* ob = QKV + ((size_t)b*QROWS + h*64) * NPIX;   // aliased out
  #pragma unroll
  for (int i = 0; i < 8; ++i) {
    const int f2 = i * 256 + tid;
    const int erow = f2 >> 5, ch = f2 & 31;   // 64 rows x 32 16B-chunks
    const uint4 v = *(const uint4*)&pool[erow * 264 + ch * 8];
    *(uint4*)&ob[(size_t)erow * NPIX + n0 + ch * 8] = v;
  }
}

// ---------------------------------------------------------------------------
// K5 (MFMA): y[c,n] = sum_e Wo[c,e]*out[e,n] + bo[c]; L2-norm over c; *g*8
// ---------------------------------------------------------------------------
__global__ __launch_bounds__(256) void k_proj(const u16* __restrict__ QKV,
    const u16* __restrict__ Wbf, const float* __restrict__ bo,
    const float* __restrict__ gg, float* __restrict__ Y)
{
  __shared__ __align__(16) u16 As[256][72];   // 36,864 B
  __shared__ __align__(16) u16 Bs[64][72];    //  9,216 B
  __shared__ float red[4][64];
  __shared__ float sbias[256], sgain[256];
  const int nt = blockIdx.x, b = blockIdx.y;
  const int n0 = nt * 64;
  const int tid = threadIdx.x;
  const int lane = tid & 63, wv = tid >> 6;
  const int g = lane >> 4, c = lane & 15;
  const u16* ob = QKV + (size_t)b * QROWS * NPIX;   // aliased out (bf16)

  sbias[tid] = bo[tid];
  sgain[tid] = gg[tid];

  f32x4 acc[4][4];
  #pragma unroll
  for (int i = 0; i < 4; ++i)
    #pragma unroll
    for (int j = 0; j < 4; ++j) acc[i][j] = (f32x4){0.f, 0.f, 0.f, 0.f};

  for (int s = 0; s < 8; ++s) {
    const int k0 = s * 64;
    #pragma unroll
    for (int i = 0; i < 8; ++i) {
      const int flat = i * 256 + tid;
      const int row = flat >> 3, kc = flat & 7;
      *(uint4*)&As[row][kc * 8] =
          *(const uint4*)&Wbf[(size_t)row * HID + k0 + kc * 8];
    }
    {
      const int kb0 = wv * 16;
      u16 vals[16];
      #pragma unroll
      for (int kk = 0; kk < 16; ++kk)
        vals[kk] = ob[(size_t)(k0 + kb0 + kk) * NPIX + n0 + lane];
      u32 pk[8];
      #pragma unroll
      for (int j = 0; j < 8; ++j)
        pk[j] = (u32)vals[2*j] | ((u32)vals[2*j+1] << 16);
      *(uint4*)&Bs[lane][kb0]     = make_uint4(pk[0], pk[1], pk[2], pk[3]);
      *(uint4*)&Bs[lane][kb0 + 8] = make_uint4(pk[4], pk[5], pk[6], pk[7]);
    }
    __syncthreads();

    #pragma unroll
    for (int ks = 0; ks < 2; ++ks) {
      bf16x8 af[4], bfr[4];
      #pragma unroll
      for (int mf = 0; mf < 4; ++mf)
        af[mf] = *(const bf16x8*)&As[wv * 64 + mf * 16 + c][ks * 32 + g * 8];
      #pragma unroll
      for (int nf = 0; nf < 4; ++nf)
        bfr[nf] = *(const bf16x8*)&Bs[nf * 16 + c][ks * 32 + g * 8];
      #pragma unroll
      for (int mf = 0; mf < 4; ++mf)
        #pragma unroll
        for (int nf = 0; nf < 4; ++nf)
          acc[mf][nf] = __builtin_amdgcn_mfma_f32_16x16x32_bf16(
              af[mf], bfr[nf], acc[mf][nf], 0, 0, 0);
    }
    __syncthreads();
  }

  #pragma unroll
  for (int mf = 0; mf < 4; ++mf)
    #pragma unroll
    for (int r = 0; r < 4; ++r) {
      const float bb = sbias[wv * 64 + mf * 16 + g * 4 + r];
      #pragma unroll
      for (int nf = 0; nf < 4; ++nf) acc[mf][nf][r] += bb;
    }

  #pragma unroll
  for (int nf = 0; nf < 4; ++nf) {
    float v = 0.f;
    #pragma unroll
    for (int mf = 0; mf < 4; ++mf)
      #pragma unroll
      for (int r = 0; r < 4; ++r)
        v = fmaf(acc[mf][nf][r], acc[mf][nf][r], v);
    v += __shfl_xor(v, 16, 64);   // reduce over g
    v += __shfl_xor(v, 32, 64);
    if (g == 0) red[wv][nf * 16 + c] = v;
  }
  __syncthreads();
  float scale[4];
  #pragma unroll
  for (int nf = 0; nf < 4; ++nf) {
    const int col = nf * 16 + c;
    const float tot = red[0][col] + red[1][col] + red[2][col] + red[3][col];
    scale[nf] = 8.0f / fmaxf(sqrtf(tot), 1e-12f);
  }

  float* yb = Y + (size_t)b * CIN * NPIX;
  #pragma unroll
  for (int mf = 0; mf < 4; ++mf)
    #pragma unroll
    for (int r = 0; r < 4; ++r) {
      const int row = wv * 64 + mf * 16 + g * 4 + r;
      const float gr = sgain[row];
      #pragma unroll
      for (int nf = 0; nf < 4; ++nf)
        yb[(size_t)row * NPIX + n0 + nf * 16 + c] = acc[mf][nf][r] * scale[nf] * gr;
    }
}

extern "C" void kernel_launch(void* const* d_in, const int* in_sizes, int n_in,
                              void* d_out, int out_size, void* d_ws, size_t ws_size,
                              hipStream_t stream) {
  const float* x     = (const float*)d_in[0];
  const float* w_qkv = (const float*)d_in[1];
  const float* w_out = (const float*)d_in[2];
  const float* b_out = (const float*)d_in[3];
  const float* g     = (const float*)d_in[4];
  float* y = (float*)d_out;

  char* ws = (char*)d_ws;
  // layout (bytes):
  //   qkv  bf16 : 16*1536*4096*2 = 201,326,592   (q-section reused as `out`)
  //   xt   bf16 : 16*4096*256*2  =  33,554,432   at 201,326,592
  //     (xt is DEAD after k_qkv; ctx/ctxp/Sp alias into its window,
  //      all written strictly after k_qkv in stream order)
  //   ctx   f32 : alias 201,392,128 (2,097,152)
  //   ctxp  f32 : alias 203,489,280 (8,388,608)
  //   Sp    f32 : alias 211,877,888 (131,072)
  //   wbf  bf16 : 234,881,024 (262,144)
  //   wqb  bf16 : 235,143,168 (786,432)
  //   total     = 235,929,600
  u16*    qkv   = (u16*)(ws);
  u16*    xt    = (u16*)(ws + 201326592);
  float*  ctx   = (float*)(ws + 201392128);
  float*  ctxp  = (float*)(ws + 203489280);
  float*  Sp    = (float*)(ws + 211877888);
  u16*    wbf   = (u16*)(ws + 234881024);
  u16*    wqb   = (u16*)(ws + 235143168);

  if (ws_size < 235929600) {
    // diagnostic marker: if this shows up as absmax ~1e6, ws_size too small
    k_marker<<<dim3((out_size + 255) / 256), 256, 0, stream>>>(y, out_size);
    return;
  }

  k_cvt   <<<dim3(64),         256, 0, stream>>>(w_out, wbf);
  k_cvt   <<<dim3(192),        256, 0, stream>>>(w_qkv, wqb);
  k_xt    <<<dim3(64, 4, 16),  256, 0, stream>>>(x, xt);
  k_qkv   <<<dim3(6144),       256, 0, stream>>>(wqb, xt, qkv);
  k_ctx   <<<dim3(4, 8, 16),   256, 0, stream>>>(qkv, ctxp, Sp);
  k_ctxred<<<dim3(512),        256, 0, stream>>>(ctxp, Sp, ctx);
  k_qctx  <<<dim3(16, 8, 16),  256, 0, stream>>>(qkv, ctx);
  k_proj  <<<dim3(64, 16),     256, 0, stream>>>(qkv, wbf, b_out, g, y);
}